// Round 8
// baseline (218.761 us; speedup 1.0000x reference)
//
#include <hip/hip_runtime.h>
#include <math.h>

#define B_SZ 256
#define N_SZ 200
#define NN (N_SZ * N_SZ)          // 40000
#define FIN 200
#define OUT_F 256
#define NCLS 8
#define KSEL 3980
#define NUPPER 20100              // N*(N+1)/2
#define KSTRIDE 20128
#define NT 7                      // ceil(200/32) tiles per dim
#define NTILES 28                 // NT*(NT+1)/2 upper tile pairs
#define CAND_CAP 2048

#define ADJ_STRIDE 224            // adj_bf16 row stride (K-padded zeros beyond 199)
#define KGRP_PB 25                // kgroups per batch (200/8)
#define XWM_PB (KGRP_PB * 2048)   // 51200 elems per batch in mfma layout

#define EMB_OFF (B_SZ * N_SZ * NCLS)               // 409600
#define ADJ_OFF (EMB_OFF + B_SZ * N_SZ * OUT_F)    // 13516800

// ---- ws layout (bytes) ----
// keys:    [0, 20,611,072)        written kA, read kFinal/kW; dead after kW
// sel:     [21,659,648, +2048)    written kFinal; read kW/kT (inside XWM region,
// candCnt: [21,661,696, +1024)     but k2 writes xwm strictly AFTER kT -- safe)
// cand:    [21,662,720, +2,097,152)
// XW_mfma: [0, 26,214,400)        aliases keys; written k2 (after kT), read k3
// w_kgrp:  [26,214,400, +114,688) bf16 w kgroup layout, 28 kgrp (3 zero)
// adjb16:  [26,329,088, +22,937,600) end 49,266,688 (< ws, proven R1-R5)
#define KEYS_OFF_B   0
#define SEL_OFF_B    21659648
#define CCNT_OFF_B   21661696
#define CAND_OFF_B   21662720
#define WKG_OFF_B    26214400
#define ADJB16_OFF_B 26329088

typedef unsigned short ushort_t;
typedef float f32x4 __attribute__((ext_vector_type(4)));
typedef short bf16x8 __attribute__((ext_vector_type(8)));

__device__ __forceinline__ unsigned sortkey(float f) {
    unsigned u = __float_as_uint(f);
    return (u & 0x80000000u) ? ~u : (u | 0x80000000u);
}

__device__ __forceinline__ ushort_t f2b(float f) {   // RNE fp32->bf16
    unsigned u = __float_as_uint(f);
    return (ushort_t)((u + 0x7FFFu + ((u >> 16) & 1u)) >> 16);
}

__device__ __forceinline__ bf16x8 f2b8(float4 lo, float4 hi) {
    bf16x8 r;
    r[0] = (short)f2b(lo.x); r[1] = (short)f2b(lo.y);
    r[2] = (short)f2b(lo.z); r[3] = (short)f2b(lo.w);
    r[4] = (short)f2b(hi.x); r[5] = (short)f2b(hi.y);
    r[6] = (short)f2b(hi.z); r[7] = (short)f2b(hi.w);
    return r;
}

__device__ __forceinline__ void tile_decode(int t, int& ti, int& tj) {
    int a = 0, rem = t;
    while (rem >= NT - a) { rem -= NT - a; ++a; }
    ti = a; tj = a + rem;
}

// -------- kA: compute sym keys (packed upper-tri) ---------------------------
__global__ __launch_bounds__(256) void kA(
    const float* __restrict__ gu, const float* __restrict__ nets,
    const int* __restrict__ net_index, unsigned* __restrict__ keys)
{
    const int blk = blockIdx.x;
    const int b = blk / NTILES;
    int ti, tj; tile_decode(blk % NTILES, ti, tj);
    const int i0 = ti * 32, j0 = tj * 32;
    const float* ub = gu + (size_t)b * NN;
    const float* lb = nets + (size_t)net_index[b] * NN;

    __shared__ float Hij[32][33];
    __shared__ float Hji[32][33];

    const int r = threadIdx.x >> 5;
    const int c = threadIdx.x & 31;

    #pragma unroll
    for (int s = 0; s < 4; ++s) {
        int rr = r + 8 * s;
        int i = i0 + rr, j = j0 + c;
        if (i < N_SZ && j < N_SZ) {
            float u = ub[i * N_SZ + j];
            u = fminf(fmaxf(u, 1e-10f), 1.0f - 1e-10f);
            Hij[rr][c] = lb[i * N_SZ + j] - logf(-logf(u));
        }
        if (ti != tj) {
            int i2 = j0 + rr, j2 = i0 + c;
            if (i2 < N_SZ && j2 < N_SZ) {
                float u = ub[i2 * N_SZ + j2];
                u = fminf(fmaxf(u, 1e-10f), 1.0f - 1e-10f);
                Hji[rr][c] = lb[i2 * N_SZ + j2] - logf(-logf(u));
            }
        }
    }
    __syncthreads();

    unsigned* kb = keys + (size_t)b * KSTRIDE;
    #pragma unroll
    for (int s = 0; s < 4; ++s) {
        int rr = r + 8 * s;
        int i = i0 + rr, j = j0 + c;
        if (i < N_SZ && j < N_SZ && i <= j) {
            float hji = (ti == tj) ? Hij[c][rr] : Hji[c][rr];
            float sv = 0.5f * (Hij[rr][c] + hji);
            int base = i * N_SZ - (i * (i - 1)) / 2;
            kb[base + (j - i)] = sortkey(sv);
        }
    }
}

// -------- kFinal: full 4-round radix select, keys LDS-resident --------------
__global__ __launch_bounds__(256) void kFinal(
    const unsigned* __restrict__ keys, unsigned* __restrict__ sel)
{
    const int b = blockIdx.x;
    const int tid = threadIdx.x;
    __shared__ unsigned kl[NUPPER];       // 80.4 KB
    __shared__ unsigned hist[256];
    __shared__ unsigned sPrefix;
    __shared__ int sKK;

    const unsigned* kb = keys + (size_t)b * KSTRIDE;
    for (int idx = tid; idx < NUPPER; idx += 256) kl[idx] = kb[idx];

    unsigned prefix = 0;
    int kk = KSEL;
    for (int round = 0; round < 4; ++round) {
        const int shift = 24 - 8 * round;
        hist[tid] = 0;
        __syncthreads();
        for (int idx = tid; idx < NUPPER; idx += 256) {
            unsigned key = kl[idx];
            bool in = (round == 0) || ((key >> (shift + 8)) == prefix);
            if (in) atomicAdd(&hist[(key >> shift) & 255u], 1u);
        }
        __syncthreads();
        if (tid == 0) {
            int cum = 0; int bsel = 0; int nkk = kk;
            for (int bn = 255; bn >= 0; --bn) {
                int cc = (int)hist[bn];
                if (cum + cc >= kk) { bsel = bn; nkk = kk - cum; break; }
                cum += cc;
            }
            sPrefix = (prefix << 8) | (unsigned)bsel;
            sKK = nkk;
        }
        __syncthreads();
        prefix = sPrefix;
        kk = sKK;
        __syncthreads();
    }
    if (tid == 0) {
        sel[b * 2] = prefix;
        sel[b * 2 + 1] = (unsigned)kk;
    }
}

// -------- kW: write 0/1 adj (fp32 + bf16 K-padded), collect exact ties ------
__global__ __launch_bounds__(256) void kW(
    const unsigned* __restrict__ keys, const unsigned* __restrict__ sel,
    unsigned* __restrict__ candCnt, unsigned* __restrict__ cand,
    float* __restrict__ out_base, ushort_t* __restrict__ adjb16)
{
    const int blk = blockIdx.x;
    const int b = blk / NTILES;
    int ti, tj; tile_decode(blk % NTILES, ti, tj);
    const int i0 = ti * 32, j0 = tj * 32;
    const unsigned kth = sel[b * 2];
    const unsigned* kb = keys + (size_t)b * KSTRIDE;
    float* adj = out_base + ADJ_OFF + (size_t)b * NN;
    ushort_t* ab = adjb16 + (size_t)b * (N_SZ * ADJ_STRIDE);

    __shared__ float V[32][33];
    const int r = threadIdx.x >> 5;
    const int c = threadIdx.x & 31;

    #pragma unroll
    for (int s = 0; s < 4; ++s) {
        int rr = r + 8 * s;
        int i = i0 + rr, j = j0 + c;
        if (i < N_SZ && j < N_SZ && i <= j) {
            int base = i * N_SZ - (i * (i - 1)) / 2;
            unsigned key = kb[base + (j - i)];
            float v = (key > kth) ? 1.0f : 0.0f;
            if (key == kth) {
                unsigned p = atomicAdd(&candCnt[b], 1u);
                if (p < CAND_CAP) cand[(size_t)b * CAND_CAP + p] = (unsigned)(i * N_SZ + j);
            }
            V[rr][c] = v;
            if (ti == tj) V[c][rr] = v;
        }
    }
    __syncthreads();
    #pragma unroll
    for (int s = 0; s < 4; ++s) {
        int rr = r + 8 * s;
        int i = i0 + rr, j = j0 + c;
        if (i < N_SZ) {
            float v = (j < N_SZ) ? V[rr][c] : 0.0f;
            if (j < N_SZ) adj[i * N_SZ + j] = v;
            ab[i * ADJ_STRIDE + j] = (v != 0.0f) ? (ushort_t)0x3F80 : (ushort_t)0;
        }
    }
    if (ti != tj) {
        #pragma unroll
        for (int s = 0; s < 4; ++s) {
            int rr = r + 8 * s;
            int i2 = j0 + rr, j2 = i0 + c;
            if (i2 < N_SZ) {
                float v = V[c][rr];
                adj[i2 * N_SZ + j2] = v;
                ab[i2 * ADJ_STRIDE + j2] = (v != 0.0f) ? (ushort_t)0x3F80 : (ushort_t)0;
            }
        }
    }
}

// -------- kT: deterministically include first-kk ties by flat index ---------
__global__ void kT(const unsigned* __restrict__ sel,
                   const unsigned* __restrict__ candCnt,
                   const unsigned* __restrict__ cand,
                   float* __restrict__ out_base, ushort_t* __restrict__ adjb16)
{
    const int b = blockIdx.x;
    if (threadIdx.x != 0) return;
    int kk = (int)sel[b * 2 + 1];
    int cnt = (int)candCnt[b];
    if (cnt > CAND_CAP) cnt = CAND_CAP;
    float* adj = out_base + ADJ_OFF + (size_t)b * NN;
    ushort_t* ab = adjb16 + (size_t)b * (N_SZ * ADJ_STRIDE);
    int take = kk < cnt ? kk : cnt;
    unsigned used[64];
    int nu = 0;
    for (int t = 0; t < take; ++t) {
        unsigned best = 0xFFFFFFFFu;
        for (int q = 0; q < cnt; ++q) {
            unsigned v = cand[(size_t)b * CAND_CAP + q];
            bool skip = false;
            for (int u = 0; u < nu; ++u) if (used[u] == v) { skip = true; break; }
            if (!skip && v < best) best = v;
        }
        if (best == 0xFFFFFFFFu) break;
        if (nu < 64) used[nu++] = best;
        int i = (int)(best / N_SZ), j = (int)(best % N_SZ);
        adj[i * N_SZ + j] = 1.0f;
        adj[j * N_SZ + i] = 1.0f;
        ab[i * ADJ_STRIDE + j] = (ushort_t)0x3F80;
        ab[j * ADJ_STRIDE + i] = (ushort_t)0x3F80;
    }
}

// -------- kWprep: w_gnn fp32 -> bf16 kgroup layout, padded to 28 kgroups ----
__global__ __launch_bounds__(256) void kWprep(
    const float* __restrict__ wg, ushort_t* __restrict__ wkg)
{
    int e = blockIdx.x * 256 + threadIdx.x;   // 224 blocks * 256 = 57344
    int kg = e >> 11;
    int rem = e & 2047;
    int n = rem >> 3;
    int ki = rem & 7;
    int k = kg * 8 + ki;
    wkg[e] = (k < FIN) ? f2b(wg[k * OUT_F + n]) : (ushort_t)0;
}

// -------- K2: XW = x @ w_gnn via bf16 MFMA, barrier-free main loop ----------
__global__ __launch_bounds__(256) void k2_mfma(
    const float* __restrict__ x, const ushort_t* __restrict__ wkg,
    ushort_t* __restrict__ xwm)
{
    const int r0 = blockIdx.x * 64;
    const int tid = threadIdx.x;
    const int w = tid >> 6;
    const int l = tid & 63;
    const int g = l >> 4;
    const int r = l & 15;

    __shared__ __align__(16) ushort_t Cs[64 * 256];   // 32 KB epilogue buffer

    f32x4 acc[4][4];
    #pragma unroll
    for (int mf = 0; mf < 4; ++mf)
        #pragma unroll
        for (int nf = 0; nf < 4; ++nf)
            acc[mf][nf] = (f32x4){0.f, 0.f, 0.f, 0.f};

    for (int c = 0; c < 7; ++c) {
        // k>=200 (chunk 6, g>0): clamp addr; B kgroups 25..27 are zero.
        const int koff = (c * 32 + g * 8 < FIN) ? (c * 32 + g * 8) : 0;
        bf16x8 af[4], bf[4];
        #pragma unroll
        for (int mf = 0; mf < 4; ++mf) {
            const float* ap = x + (size_t)(r0 + mf * 16 + r) * FIN + koff;
            float4 lo = *(const float4*)ap;
            float4 hi = *(const float4*)(ap + 4);
            af[mf] = f2b8(lo, hi);
        }
        #pragma unroll
        for (int nf = 0; nf < 4; ++nf)
            bf[nf] = *(const bf16x8*)(wkg + c * 8192 + g * 2048 + (w * 64 + nf * 16 + r) * 8);
        #pragma unroll
        for (int mf = 0; mf < 4; ++mf)
            #pragma unroll
            for (int nf = 0; nf < 4; ++nf)
                acc[mf][nf] = __builtin_amdgcn_mfma_f32_16x16x32_bf16(
                    af[mf], bf[nf], acc[mf][nf], 0, 0, 0);
    }

    // scatter to Cs in kgroup layout (local rows 0..63)
    #pragma unroll
    for (int mf = 0; mf < 4; ++mf) {
        #pragma unroll
        for (int jj = 0; jj < 4; ++jj) {
            int row = mf * 16 + g * 4 + jj;
            #pragma unroll
            for (int nf = 0; nf < 4; ++nf) {
                int col = w * 64 + nf * 16 + r;
                Cs[((row >> 3) << 11) + col * 8 + (row & 7)] = f2b(acc[mf][nf][jj]);
            }
        }
    }
    __syncthreads();
    // linear write-out: 8 local kgroups (8-row groups never cross batch bound)
    #pragma unroll
    for (int kg = 0; kg < 8; ++kg) {
        int grow0 = r0 + kg * 8;
        int bb = grow0 / N_SZ;
        int jb = grow0 % N_SZ;
        ushort_t* dst = xwm + (size_t)bb * XWM_PB + ((jb >> 3) << 11);
        *(int4*)(dst + tid * 8) = *(const int4*)(Cs + (kg << 11) + tid * 8);
    }
}

// -------- K3: emb = relu(adj @ XW) via bf16 MFMA, zero-LDS zero-barrier -----
// A direct from adjb16 (fragment-ready, K-padded). XCD-bijective block decode.
__global__ __launch_bounds__(256) void k3_mfma(
    const ushort_t* __restrict__ adjb16, const ushort_t* __restrict__ xwm,
    float* __restrict__ out_base)
{
    const int blk = blockIdx.x;
    const int b = (blk & 7) + 8 * (blk >> 5);
    const int mt = (blk >> 3) & 3;
    const int tid = threadIdx.x;
    const int w = tid >> 6;
    const int l = tid & 63;
    const int g = l >> 4;
    const int r = l & 15;

    const ushort_t* adjb = adjb16 + (size_t)b * (N_SZ * ADJ_STRIDE);
    const ushort_t* xwb = xwm + (size_t)b * XWM_PB;

    f32x4 acc[4][4];
    #pragma unroll
    for (int mf = 0; mf < 4; ++mf)
        #pragma unroll
        for (int nf = 0; nf < 4; ++nf)
            acc[mf][nf] = (f32x4){0.f, 0.f, 0.f, 0.f};

    int arows[4];
    #pragma unroll
    for (int mf = 0; mf < 4; ++mf) {
        int row = mt * 64 + mf * 16 + r;
        arows[mf] = (row < N_SZ) ? row : (N_SZ - 1);
    }

    for (int c = 0; c < 7; ++c) {
        bf16x8 af[4], bf[4];
        #pragma unroll
        for (int mf = 0; mf < 4; ++mf)
            af[mf] = *(const bf16x8*)(adjb + arows[mf] * ADJ_STRIDE + c * 32 + g * 8);
        // chunk 6, g>0 reads kgroups 25..27 (next batch / wkg: finite);
        // A is zero there (adjb16 K-padding) so product vanishes.
        #pragma unroll
        for (int nf = 0; nf < 4; ++nf)
            bf[nf] = *(const bf16x8*)(xwb + c * 8192 + g * 2048 + (w * 64 + nf * 16 + r) * 8);
        #pragma unroll
        for (int mf = 0; mf < 4; ++mf)
            #pragma unroll
            for (int nf = 0; nf < 4; ++nf)
                acc[mf][nf] = __builtin_amdgcn_mfma_f32_16x16x32_bf16(
                    af[mf], bf[nf], acc[mf][nf], 0, 0, 0);
    }

    #pragma unroll
    for (int mf = 0; mf < 4; ++mf) {
        #pragma unroll
        for (int j = 0; j < 4; ++j) {
            int rowl = mf * 16 + g * 4 + j;
            int grow2 = mt * 64 + rowl;
            if (grow2 < N_SZ) {
                size_t rbase = EMB_OFF + ((size_t)b * N_SZ + grow2) * OUT_F;
                #pragma unroll
                for (int nf = 0; nf < 4; ++nf) {
                    int col = w * 64 + nf * 16 + r;
                    out_base[rbase + col] = fmaxf(acc[mf][nf][j], 0.0f);
                }
            }
        }
    }
}

// -------- K4: out = emb @ w_lin + b  (1 row per wave, 4 rows per block) -----
__global__ __launch_bounds__(256) void k4_out(
    const float* __restrict__ wl, const float* __restrict__ bl,
    float* __restrict__ out_base)
{
    const int wave = threadIdx.x >> 6;
    const int lane = threadIdx.x & 63;
    const int row = blockIdx.x * 4 + wave;    // 12800 blocks

    float4 e = *(const float4*)(out_base + EMB_OFF + (size_t)row * OUT_F + lane * 4);
    const float* wp = wl + (size_t)lane * 4 * NCLS;
    float pr[NCLS];
    #pragma unroll
    for (int c = 0; c < NCLS; ++c)
        pr[c] = e.x * wp[c] + e.y * wp[NCLS + c] + e.z * wp[2 * NCLS + c] + e.w * wp[3 * NCLS + c];
    #pragma unroll
    for (int c = 0; c < NCLS; ++c) {
        #pragma unroll
        for (int off = 32; off >= 1; off >>= 1)
            pr[c] += __shfl_xor(pr[c], off, 64);
    }
    if (lane == 0) {
        float4 o0 = {pr[0] + bl[0], pr[1] + bl[1], pr[2] + bl[2], pr[3] + bl[3]};
        float4 o1 = {pr[4] + bl[4], pr[5] + bl[5], pr[6] + bl[6], pr[7] + bl[7]};
        *(float4*)(out_base + (size_t)row * NCLS) = o0;
        *(float4*)(out_base + (size_t)row * NCLS + 4) = o1;
    }
}

extern "C" void kernel_launch(void* const* d_in, const int* in_sizes, int n_in,
                              void* d_out, int out_size, void* d_ws, size_t ws_size,
                              hipStream_t stream) {
    const float* x    = (const float*)d_in[0];
    const float* gu   = (const float*)d_in[1];
    const float* nets = (const float*)d_in[2];
    const float* wg   = (const float*)d_in[3];
    const float* wl   = (const float*)d_in[4];
    const float* bl   = (const float*)d_in[5];
    const int*   nidx = (const int*)d_in[6];
    float* out = (float*)d_out;

    char* ws = (char*)d_ws;
    unsigned* keys    = (unsigned*)(ws + KEYS_OFF_B);
    unsigned* sel     = (unsigned*)(ws + SEL_OFF_B);
    unsigned* candCnt = (unsigned*)(ws + CCNT_OFF_B);
    unsigned* cand    = (unsigned*)(ws + CAND_OFF_B);
    ushort_t* xwm     = (ushort_t*)(ws + KEYS_OFF_B);   // aliases keys; k2 after kT
    ushort_t* wkg     = (ushort_t*)(ws + WKG_OFF_B);
    ushort_t* adjb16  = (ushort_t*)(ws + ADJB16_OFF_B);

    hipMemsetAsync(ws + CCNT_OFF_B, 0, 1024, stream);

    kWprep<<<224, 256, 0, stream>>>(wg, wkg);
    kA<<<B_SZ * NTILES, 256, 0, stream>>>(gu, nets, nidx, keys);
    kFinal<<<B_SZ, 256, 0, stream>>>(keys, sel);
    kW<<<B_SZ * NTILES, 256, 0, stream>>>(keys, sel, candCnt, cand, out, adjb16);
    kT<<<B_SZ, 64, 0, stream>>>(sel, candCnt, cand, out, adjb16);

    k2_mfma<<<(B_SZ * N_SZ) / 64, 256, 0, stream>>>(x, wkg, xwm);
    k3_mfma<<<B_SZ * 4, 256, 0, stream>>>(adjb16, xwm, out);
    k4_out<<<(B_SZ * N_SZ) / 4, 256, 0, stream>>>(wl, bl, out);
}

// Round 9
// 190.544 us; speedup vs baseline: 1.1481x; 1.1481x over previous
//
#include <hip/hip_runtime.h>
#include <math.h>

#define B_SZ 256
#define N_SZ 200
#define NN (N_SZ * N_SZ)          // 40000
#define FIN 200
#define OUT_F 256
#define NCLS 8
#define KSEL 3980
#define NUPPER 20100              // N*(N+1)/2
#define KSTRIDE 20128
#define NT 7                      // ceil(200/32) tiles per dim
#define NTILES 28                 // NT*(NT+1)/2 upper tile pairs
#define CAND_CAP 2048

#define ADJ_STRIDE 224            // adj_bf16 row stride (K-padded zeros beyond 199)
#define KGRP_PB 25                // kgroups per batch (200/8)
#define XWM_PB (KGRP_PB * 2048)   // 51200 elems per batch in mfma layout

#define EMB_OFF (B_SZ * N_SZ * NCLS)               // 409600
#define ADJ_OFF (EMB_OFF + B_SZ * N_SZ * OUT_F)    // 13516800

// ---- ws layout (bytes) ----
// keys:    [0, 20,611,072)        written kA, read kFinal/kW; dead after kW
// sel:     [21,659,648, +2048)    written kFinal; read kW/kT (inside XWM region,
// candCnt: [21,661,696, +1024)     but k2 writes xwm strictly AFTER kT -- safe)
// cand:    [21,662,720, +2,097,152)
// XW_mfma: [0, 26,214,400)        aliases keys; written k2 (after kT), read k3
// w_kgrp:  [26,214,400, +114,688) bf16 w kgroup layout, 28 kgrp (3 zero)
// adjb16:  [26,329,088, +22,937,600) end 49,266,688 (< ws, proven R1-R5)
#define KEYS_OFF_B   0
#define SEL_OFF_B    21659648
#define CCNT_OFF_B   21661696
#define CAND_OFF_B   21662720
#define WKG_OFF_B    26214400
#define ADJB16_OFF_B 26329088

typedef unsigned short ushort_t;
typedef float f32x4 __attribute__((ext_vector_type(4)));
typedef short bf16x8 __attribute__((ext_vector_type(8)));

__device__ __forceinline__ unsigned sortkey(float f) {
    unsigned u = __float_as_uint(f);
    return (u & 0x80000000u) ? ~u : (u | 0x80000000u);
}

__device__ __forceinline__ ushort_t f2b(float f) {   // RNE fp32->bf16
    unsigned u = __float_as_uint(f);
    return (ushort_t)((u + 0x7FFFu + ((u >> 16) & 1u)) >> 16);
}

__device__ __forceinline__ bf16x8 f2b8(float4 lo, float4 hi) {
    bf16x8 r;
    r[0] = (short)f2b(lo.x); r[1] = (short)f2b(lo.y);
    r[2] = (short)f2b(lo.z); r[3] = (short)f2b(lo.w);
    r[4] = (short)f2b(hi.x); r[5] = (short)f2b(hi.y);
    r[6] = (short)f2b(hi.z); r[7] = (short)f2b(hi.w);
    return r;
}

__device__ __forceinline__ void tile_decode(int t, int& ti, int& tj) {
    int a = 0, rem = t;
    while (rem >= NT - a) { rem -= NT - a; ++a; }
    ti = a; tj = a + rem;
}

// -------- kA: compute sym keys (packed upper-tri) ---------------------------
__global__ __launch_bounds__(256) void kA(
    const float* __restrict__ gu, const float* __restrict__ nets,
    const int* __restrict__ net_index, unsigned* __restrict__ keys)
{
    const int blk = blockIdx.x;
    const int b = blk / NTILES;
    int ti, tj; tile_decode(blk % NTILES, ti, tj);
    const int i0 = ti * 32, j0 = tj * 32;
    const float* ub = gu + (size_t)b * NN;
    const float* lb = nets + (size_t)net_index[b] * NN;

    __shared__ float Hij[32][33];
    __shared__ float Hji[32][33];

    const int r = threadIdx.x >> 5;
    const int c = threadIdx.x & 31;

    #pragma unroll
    for (int s = 0; s < 4; ++s) {
        int rr = r + 8 * s;
        int i = i0 + rr, j = j0 + c;
        if (i < N_SZ && j < N_SZ) {
            float u = ub[i * N_SZ + j];
            u = fminf(fmaxf(u, 1e-10f), 1.0f - 1e-10f);
            Hij[rr][c] = lb[i * N_SZ + j] - logf(-logf(u));
        }
        if (ti != tj) {
            int i2 = j0 + rr, j2 = i0 + c;
            if (i2 < N_SZ && j2 < N_SZ) {
                float u = ub[i2 * N_SZ + j2];
                u = fminf(fmaxf(u, 1e-10f), 1.0f - 1e-10f);
                Hji[rr][c] = lb[i2 * N_SZ + j2] - logf(-logf(u));
            }
        }
    }
    __syncthreads();

    unsigned* kb = keys + (size_t)b * KSTRIDE;
    #pragma unroll
    for (int s = 0; s < 4; ++s) {
        int rr = r + 8 * s;
        int i = i0 + rr, j = j0 + c;
        if (i < N_SZ && j < N_SZ && i <= j) {
            float hji = (ti == tj) ? Hij[c][rr] : Hji[c][rr];
            float sv = 0.5f * (Hij[rr][c] + hji);
            int base = i * N_SZ - (i * (i - 1)) / 2;
            kb[base + (j - i)] = sortkey(sv);
        }
    }
}

// -------- kFinal: 4-round radix select, keys LDS-resident, parallel select --
__global__ __launch_bounds__(256) void kFinal(
    const unsigned* __restrict__ keys, unsigned* __restrict__ sel)
{
    const int b = blockIdx.x;
    const int tid = threadIdx.x;
    __shared__ unsigned kl[NUPPER];       // 80.4 KB
    __shared__ unsigned hist[256];
    __shared__ unsigned sfx[256];
    __shared__ unsigned sPrefix;
    __shared__ int sKK;

    const unsigned* kb = keys + (size_t)b * KSTRIDE;
    for (int idx = tid; idx < NUPPER; idx += 256) kl[idx] = kb[idx];

    unsigned prefix = 0;
    int kk = KSEL;
    for (int round = 0; round < 4; ++round) {
        const int shift = 24 - 8 * round;
        hist[tid] = 0;
        __syncthreads();
        for (int idx = tid; idx < NUPPER; idx += 256) {
            unsigned key = kl[idx];
            bool in = (round == 0) || ((key >> (shift + 8)) == prefix);
            if (in) atomicAdd(&hist[(key >> shift) & 255u], 1u);
        }
        __syncthreads();
        // parallel inclusive suffix sum: sfx[t] = sum_{u>=t} hist[u]
        sfx[tid] = hist[tid];
        __syncthreads();
        #pragma unroll
        for (int off = 1; off < 256; off <<= 1) {
            unsigned add = (tid + off < 256) ? sfx[tid + off] : 0u;
            __syncthreads();
            sfx[tid] += add;
            __syncthreads();
        }
        // unique thread: sfx[t] >= kk > sfx[t+1]  (sfx monotone non-increasing)
        unsigned above = (tid < 255) ? sfx[tid + 1] : 0u;
        if (sfx[tid] >= (unsigned)kk && above < (unsigned)kk) {
            sPrefix = (prefix << 8) | (unsigned)tid;
            sKK = kk - (int)above;
        }
        __syncthreads();
        prefix = sPrefix;
        kk = sKK;
        __syncthreads();
    }
    if (tid == 0) {
        sel[b * 2] = prefix;
        sel[b * 2 + 1] = (unsigned)kk;
    }
}

// -------- kW: write 0/1 adj (fp32 + bf16 K-padded), collect exact ties ------
__global__ __launch_bounds__(256) void kW(
    const unsigned* __restrict__ keys, const unsigned* __restrict__ sel,
    unsigned* __restrict__ candCnt, unsigned* __restrict__ cand,
    float* __restrict__ out_base, ushort_t* __restrict__ adjb16)
{
    const int blk = blockIdx.x;
    const int b = blk / NTILES;
    int ti, tj; tile_decode(blk % NTILES, ti, tj);
    const int i0 = ti * 32, j0 = tj * 32;
    const unsigned kth = sel[b * 2];
    const unsigned* kb = keys + (size_t)b * KSTRIDE;
    float* adj = out_base + ADJ_OFF + (size_t)b * NN;
    ushort_t* ab = adjb16 + (size_t)b * (N_SZ * ADJ_STRIDE);

    __shared__ float V[32][33];
    const int r = threadIdx.x >> 5;
    const int c = threadIdx.x & 31;

    #pragma unroll
    for (int s = 0; s < 4; ++s) {
        int rr = r + 8 * s;
        int i = i0 + rr, j = j0 + c;
        if (i < N_SZ && j < N_SZ && i <= j) {
            int base = i * N_SZ - (i * (i - 1)) / 2;
            unsigned key = kb[base + (j - i)];
            float v = (key > kth) ? 1.0f : 0.0f;
            if (key == kth) {
                unsigned p = atomicAdd(&candCnt[b], 1u);
                if (p < CAND_CAP) cand[(size_t)b * CAND_CAP + p] = (unsigned)(i * N_SZ + j);
            }
            V[rr][c] = v;
            if (ti == tj) V[c][rr] = v;
        }
    }
    __syncthreads();
    #pragma unroll
    for (int s = 0; s < 4; ++s) {
        int rr = r + 8 * s;
        int i = i0 + rr, j = j0 + c;
        if (i < N_SZ) {
            float v = (j < N_SZ) ? V[rr][c] : 0.0f;
            if (j < N_SZ) adj[i * N_SZ + j] = v;
            ab[i * ADJ_STRIDE + j] = (v != 0.0f) ? (ushort_t)0x3F80 : (ushort_t)0;
        }
    }
    if (ti != tj) {
        #pragma unroll
        for (int s = 0; s < 4; ++s) {
            int rr = r + 8 * s;
            int i2 = j0 + rr, j2 = i0 + c;
            if (i2 < N_SZ) {
                float v = V[c][rr];
                adj[i2 * N_SZ + j2] = v;
                ab[i2 * ADJ_STRIDE + j2] = (v != 0.0f) ? (ushort_t)0x3F80 : (ushort_t)0;
            }
        }
    }
}

// -------- kT: deterministically include first-kk ties by flat index ---------
__global__ void kT(const unsigned* __restrict__ sel,
                   const unsigned* __restrict__ candCnt,
                   const unsigned* __restrict__ cand,
                   float* __restrict__ out_base, ushort_t* __restrict__ adjb16)
{
    const int b = blockIdx.x;
    if (threadIdx.x != 0) return;
    int kk = (int)sel[b * 2 + 1];
    int cnt = (int)candCnt[b];
    if (cnt > CAND_CAP) cnt = CAND_CAP;
    float* adj = out_base + ADJ_OFF + (size_t)b * NN;
    ushort_t* ab = adjb16 + (size_t)b * (N_SZ * ADJ_STRIDE);
    int take = kk < cnt ? kk : cnt;
    unsigned used[64];
    int nu = 0;
    for (int t = 0; t < take; ++t) {
        unsigned best = 0xFFFFFFFFu;
        for (int q = 0; q < cnt; ++q) {
            unsigned v = cand[(size_t)b * CAND_CAP + q];
            bool skip = false;
            for (int u = 0; u < nu; ++u) if (used[u] == v) { skip = true; break; }
            if (!skip && v < best) best = v;
        }
        if (best == 0xFFFFFFFFu) break;
        if (nu < 64) used[nu++] = best;
        int i = (int)(best / N_SZ), j = (int)(best % N_SZ);
        adj[i * N_SZ + j] = 1.0f;
        adj[j * N_SZ + i] = 1.0f;
        ab[i * ADJ_STRIDE + j] = (ushort_t)0x3F80;
        ab[j * ADJ_STRIDE + i] = (ushort_t)0x3F80;
    }
}

// -------- kWprep: w_gnn fp32 -> bf16 kgroup layout, padded to 28 kgroups ----
__global__ __launch_bounds__(256) void kWprep(
    const float* __restrict__ wg, ushort_t* __restrict__ wkg)
{
    int e = blockIdx.x * 256 + threadIdx.x;   // 224 blocks * 256 = 57344
    int kg = e >> 11;
    int rem = e & 2047;
    int n = rem >> 3;
    int ki = rem & 7;
    int k = kg * 8 + ki;
    wkg[e] = (k < FIN) ? f2b(wg[k * OUT_F + n]) : (ushort_t)0;
}

// -------- K2: XW = x @ w_gnn via bf16 MFMA, barrier-free main loop ----------
__global__ __launch_bounds__(256) void k2_mfma(
    const float* __restrict__ x, const ushort_t* __restrict__ wkg,
    ushort_t* __restrict__ xwm)
{
    const int r0 = blockIdx.x * 64;
    const int tid = threadIdx.x;
    const int w = tid >> 6;
    const int l = tid & 63;
    const int g = l >> 4;
    const int r = l & 15;

    __shared__ __align__(16) ushort_t Cs[64 * 256];   // 32 KB epilogue buffer

    f32x4 acc[4][4];
    #pragma unroll
    for (int mf = 0; mf < 4; ++mf)
        #pragma unroll
        for (int nf = 0; nf < 4; ++nf)
            acc[mf][nf] = (f32x4){0.f, 0.f, 0.f, 0.f};

    for (int c = 0; c < 7; ++c) {
        // k>=200 (chunk 6, g>0): clamp addr; B kgroups 25..27 are zero.
        const int koff = (c * 32 + g * 8 < FIN) ? (c * 32 + g * 8) : 0;
        bf16x8 af[4], bf[4];
        #pragma unroll
        for (int mf = 0; mf < 4; ++mf) {
            const float* ap = x + (size_t)(r0 + mf * 16 + r) * FIN + koff;
            float4 lo = *(const float4*)ap;
            float4 hi = *(const float4*)(ap + 4);
            af[mf] = f2b8(lo, hi);
        }
        #pragma unroll
        for (int nf = 0; nf < 4; ++nf)
            bf[nf] = *(const bf16x8*)(wkg + c * 8192 + g * 2048 + (w * 64 + nf * 16 + r) * 8);
        #pragma unroll
        for (int mf = 0; mf < 4; ++mf)
            #pragma unroll
            for (int nf = 0; nf < 4; ++nf)
                acc[mf][nf] = __builtin_amdgcn_mfma_f32_16x16x32_bf16(
                    af[mf], bf[nf], acc[mf][nf], 0, 0, 0);
    }

    // scatter to Cs in kgroup layout (local rows 0..63)
    #pragma unroll
    for (int mf = 0; mf < 4; ++mf) {
        #pragma unroll
        for (int jj = 0; jj < 4; ++jj) {
            int row = mf * 16 + g * 4 + jj;
            #pragma unroll
            for (int nf = 0; nf < 4; ++nf) {
                int col = w * 64 + nf * 16 + r;
                Cs[((row >> 3) << 11) + col * 8 + (row & 7)] = f2b(acc[mf][nf][jj]);
            }
        }
    }
    __syncthreads();
    // linear write-out: 8 local kgroups (8-row groups never cross batch bound)
    #pragma unroll
    for (int kg = 0; kg < 8; ++kg) {
        int grow0 = r0 + kg * 8;
        int bb = grow0 / N_SZ;
        int jb = grow0 % N_SZ;
        ushort_t* dst = xwm + (size_t)bb * XWM_PB + ((jb >> 3) << 11);
        *(int4*)(dst + tid * 8) = *(const int4*)(Cs + (kg << 11) + tid * 8);
    }
}

// -------- K3: emb = relu(adj @ XW) via bf16 MFMA, zero-LDS zero-barrier -----
// A direct from adjb16 (fragment-ready, K-padded). XCD-bijective block decode.
__global__ __launch_bounds__(256) void k3_mfma(
    const ushort_t* __restrict__ adjb16, const ushort_t* __restrict__ xwm,
    float* __restrict__ out_base)
{
    const int blk = blockIdx.x;
    const int b = (blk & 7) + 8 * (blk >> 5);
    const int mt = (blk >> 3) & 3;
    const int tid = threadIdx.x;
    const int w = tid >> 6;
    const int l = tid & 63;
    const int g = l >> 4;
    const int r = l & 15;

    const ushort_t* adjb = adjb16 + (size_t)b * (N_SZ * ADJ_STRIDE);
    const ushort_t* xwb = xwm + (size_t)b * XWM_PB;

    f32x4 acc[4][4];
    #pragma unroll
    for (int mf = 0; mf < 4; ++mf)
        #pragma unroll
        for (int nf = 0; nf < 4; ++nf)
            acc[mf][nf] = (f32x4){0.f, 0.f, 0.f, 0.f};

    int arows[4];
    #pragma unroll
    for (int mf = 0; mf < 4; ++mf) {
        int row = mt * 64 + mf * 16 + r;
        arows[mf] = (row < N_SZ) ? row : (N_SZ - 1);
    }

    for (int c = 0; c < 7; ++c) {
        bf16x8 af[4], bf[4];
        #pragma unroll
        for (int mf = 0; mf < 4; ++mf)
            af[mf] = *(const bf16x8*)(adjb + arows[mf] * ADJ_STRIDE + c * 32 + g * 8);
        // chunk 6, g>0 reads kgroups 25..27 (next batch / wkg: finite);
        // A is zero there (adjb16 K-padding) so product vanishes.
        #pragma unroll
        for (int nf = 0; nf < 4; ++nf)
            bf[nf] = *(const bf16x8*)(xwb + c * 8192 + g * 2048 + (w * 64 + nf * 16 + r) * 8);
        #pragma unroll
        for (int mf = 0; mf < 4; ++mf)
            #pragma unroll
            for (int nf = 0; nf < 4; ++nf)
                acc[mf][nf] = __builtin_amdgcn_mfma_f32_16x16x32_bf16(
                    af[mf], bf[nf], acc[mf][nf], 0, 0, 0);
    }

    #pragma unroll
    for (int mf = 0; mf < 4; ++mf) {
        #pragma unroll
        for (int j = 0; j < 4; ++j) {
            int rowl = mf * 16 + g * 4 + j;
            int grow2 = mt * 64 + rowl;
            if (grow2 < N_SZ) {
                size_t rbase = EMB_OFF + ((size_t)b * N_SZ + grow2) * OUT_F;
                #pragma unroll
                for (int nf = 0; nf < 4; ++nf) {
                    int col = w * 64 + nf * 16 + r;
                    out_base[rbase + col] = fmaxf(acc[mf][nf][j], 0.0f);
                }
            }
        }
    }
}

// -------- K4: out = emb @ w_lin + b  (1 row per wave, 4 rows per block) -----
__global__ __launch_bounds__(256) void k4_out(
    const float* __restrict__ wl, const float* __restrict__ bl,
    float* __restrict__ out_base)
{
    const int wave = threadIdx.x >> 6;
    const int lane = threadIdx.x & 63;
    const int row = blockIdx.x * 4 + wave;    // 12800 blocks

    float4 e = *(const float4*)(out_base + EMB_OFF + (size_t)row * OUT_F + lane * 4);
    const float* wp = wl + (size_t)lane * 4 * NCLS;
    float pr[NCLS];
    #pragma unroll
    for (int c = 0; c < NCLS; ++c)
        pr[c] = e.x * wp[c] + e.y * wp[NCLS + c] + e.z * wp[2 * NCLS + c] + e.w * wp[3 * NCLS + c];
    #pragma unroll
    for (int c = 0; c < NCLS; ++c) {
        #pragma unroll
        for (int off = 32; off >= 1; off >>= 1)
            pr[c] += __shfl_xor(pr[c], off, 64);
    }
    if (lane == 0) {
        float4 o0 = {pr[0] + bl[0], pr[1] + bl[1], pr[2] + bl[2], pr[3] + bl[3]};
        float4 o1 = {pr[4] + bl[4], pr[5] + bl[5], pr[6] + bl[6], pr[7] + bl[7]};
        *(float4*)(out_base + (size_t)row * NCLS) = o0;
        *(float4*)(out_base + (size_t)row * NCLS + 4) = o1;
    }
}

extern "C" void kernel_launch(void* const* d_in, const int* in_sizes, int n_in,
                              void* d_out, int out_size, void* d_ws, size_t ws_size,
                              hipStream_t stream) {
    const float* x    = (const float*)d_in[0];
    const float* gu   = (const float*)d_in[1];
    const float* nets = (const float*)d_in[2];
    const float* wg   = (const float*)d_in[3];
    const float* wl   = (const float*)d_in[4];
    const float* bl   = (const float*)d_in[5];
    const int*   nidx = (const int*)d_in[6];
    float* out = (float*)d_out;

    char* ws = (char*)d_ws;
    unsigned* keys    = (unsigned*)(ws + KEYS_OFF_B);
    unsigned* sel     = (unsigned*)(ws + SEL_OFF_B);
    unsigned* candCnt = (unsigned*)(ws + CCNT_OFF_B);
    unsigned* cand    = (unsigned*)(ws + CAND_OFF_B);
    ushort_t* xwm     = (ushort_t*)(ws + KEYS_OFF_B);   // aliases keys; k2 after kT
    ushort_t* wkg     = (ushort_t*)(ws + WKG_OFF_B);
    ushort_t* adjb16  = (ushort_t*)(ws + ADJB16_OFF_B);

    hipMemsetAsync(ws + CCNT_OFF_B, 0, 1024, stream);

    kWprep<<<224, 256, 0, stream>>>(wg, wkg);
    kA<<<B_SZ * NTILES, 256, 0, stream>>>(gu, nets, nidx, keys);
    kFinal<<<B_SZ, 256, 0, stream>>>(keys, sel);
    kW<<<B_SZ * NTILES, 256, 0, stream>>>(keys, sel, candCnt, cand, out, adjb16);
    kT<<<B_SZ, 64, 0, stream>>>(sel, candCnt, cand, out, adjb16);

    k2_mfma<<<(B_SZ * N_SZ) / 64, 256, 0, stream>>>(x, wkg, xwm);
    k3_mfma<<<B_SZ * 4, 256, 0, stream>>>(adjb16, xwm, out);
    k4_out<<<(B_SZ * N_SZ) / 4, 256, 0, stream>>>(wl, bl, out);
}

// Round 10
// 160.306 us; speedup vs baseline: 1.3646x; 1.1886x over previous
//
#include <hip/hip_runtime.h>
#include <math.h>

#define B_SZ 256
#define N_SZ 200
#define NN (N_SZ * N_SZ)          // 40000
#define FIN 200
#define OUT_F 256
#define NCLS 8
#define KSEL 3980
#define NUPPER 20100              // N*(N+1)/2
#define KSTRIDE 20128
#define NT 7                      // ceil(200/32) tiles per dim
#define NTILES 28                 // NT*(NT+1)/2 upper tile pairs
#define CAND_CAP 2048

#define ADJ_STRIDE 224            // adj_bf16 row stride (K-padded zeros beyond 199)
#define KGRP_PB 25                // kgroups per batch (200/8)
#define XWM_PB (KGRP_PB * 2048)   // 51200 elems per batch in mfma layout

#define EMB_OFF (B_SZ * N_SZ * NCLS)               // 409600
#define ADJ_OFF (EMB_OFF + B_SZ * N_SZ * OUT_F)    // 13516800

// ---- ws layout (bytes) ----
// keys:    [0, 20,611,072)        written kA, read kFinal/kW; dead after kW
// sel:     [21,659,648, +2048)    written kFinal; read kW/kT (inside XWM region,
// candCnt: [21,661,696, +1024)     but k2 writes xwm strictly AFTER kT -- safe)
// cand:    [21,662,720, +2,097,152)
// XW_mfma: [0, 26,214,400)        aliases keys; written k2 (after kT), read k3
// w_kgrp:  [26,214,400, +114,688) bf16 w kgroup layout, 28 kgrp (3 zero)
// adjb16:  [26,329,088, +22,937,600) end 49,266,688 (< ws, proven R1-R5)
#define KEYS_OFF_B   0
#define SEL_OFF_B    21659648
#define CCNT_OFF_B   21661696
#define CAND_OFF_B   21662720
#define WKG_OFF_B    26214400
#define ADJB16_OFF_B 26329088

typedef unsigned short ushort_t;
typedef float f32x4 __attribute__((ext_vector_type(4)));
typedef short bf16x8 __attribute__((ext_vector_type(8)));

__device__ __forceinline__ unsigned sortkey(float f) {
    unsigned u = __float_as_uint(f);
    return (u & 0x80000000u) ? ~u : (u | 0x80000000u);
}

__device__ __forceinline__ ushort_t f2b(float f) {   // RNE fp32->bf16
    unsigned u = __float_as_uint(f);
    return (ushort_t)((u + 0x7FFFu + ((u >> 16) & 1u)) >> 16);
}

__device__ __forceinline__ bf16x8 f2b8(float4 lo, float4 hi) {
    bf16x8 r;
    r[0] = (short)f2b(lo.x); r[1] = (short)f2b(lo.y);
    r[2] = (short)f2b(lo.z); r[3] = (short)f2b(lo.w);
    r[4] = (short)f2b(hi.x); r[5] = (short)f2b(hi.y);
    r[6] = (short)f2b(hi.z); r[7] = (short)f2b(hi.w);
    return r;
}

__device__ __forceinline__ void tile_decode(int t, int& ti, int& tj) {
    int a = 0, rem = t;
    while (rem >= NT - a) { rem -= NT - a; ++a; }
    ti = a; tj = a + rem;
}

// -------- kA: compute sym keys (packed upper-tri) ---------------------------
__global__ __launch_bounds__(256) void kA(
    const float* __restrict__ gu, const float* __restrict__ nets,
    const int* __restrict__ net_index, unsigned* __restrict__ keys)
{
    const int blk = blockIdx.x;
    const int b = blk / NTILES;
    int ti, tj; tile_decode(blk % NTILES, ti, tj);
    const int i0 = ti * 32, j0 = tj * 32;
    const float* ub = gu + (size_t)b * NN;
    const float* lb = nets + (size_t)net_index[b] * NN;

    __shared__ float Hij[32][33];
    __shared__ float Hji[32][33];

    const int r = threadIdx.x >> 5;
    const int c = threadIdx.x & 31;

    #pragma unroll
    for (int s = 0; s < 4; ++s) {
        int rr = r + 8 * s;
        int i = i0 + rr, j = j0 + c;
        if (i < N_SZ && j < N_SZ) {
            float u = ub[i * N_SZ + j];
            u = fminf(fmaxf(u, 1e-10f), 1.0f - 1e-10f);
            Hij[rr][c] = lb[i * N_SZ + j] - logf(-logf(u));
        }
        if (ti != tj) {
            int i2 = j0 + rr, j2 = i0 + c;
            if (i2 < N_SZ && j2 < N_SZ) {
                float u = ub[i2 * N_SZ + j2];
                u = fminf(fmaxf(u, 1e-10f), 1.0f - 1e-10f);
                Hji[rr][c] = lb[i2 * N_SZ + j2] - logf(-logf(u));
            }
        }
    }
    __syncthreads();

    unsigned* kb = keys + (size_t)b * KSTRIDE;
    #pragma unroll
    for (int s = 0; s < 4; ++s) {
        int rr = r + 8 * s;
        int i = i0 + rr, j = j0 + c;
        if (i < N_SZ && j < N_SZ && i <= j) {
            float hji = (ti == tj) ? Hij[c][rr] : Hji[c][rr];
            float sv = 0.5f * (Hij[rr][c] + hji);
            int base = i * N_SZ - (i * (i - 1)) / 2;
            kb[base + (j - i)] = sortkey(sv);
        }
    }
}

// -------- kFinal: 4-round radix select, keys LDS-resident, parallel select --
__global__ __launch_bounds__(256) void kFinal(
    const unsigned* __restrict__ keys, unsigned* __restrict__ sel)
{
    const int b = blockIdx.x;
    const int tid = threadIdx.x;
    __shared__ unsigned kl[NUPPER];       // 80.4 KB
    __shared__ unsigned hist[256];
    __shared__ unsigned sfx[256];
    __shared__ unsigned sPrefix;
    __shared__ int sKK;

    const unsigned* kb = keys + (size_t)b * KSTRIDE;
    for (int idx = tid; idx < NUPPER; idx += 256) kl[idx] = kb[idx];

    unsigned prefix = 0;
    int kk = KSEL;
    for (int round = 0; round < 4; ++round) {
        const int shift = 24 - 8 * round;
        hist[tid] = 0;
        __syncthreads();
        for (int idx = tid; idx < NUPPER; idx += 256) {
            unsigned key = kl[idx];
            bool in = (round == 0) || ((key >> (shift + 8)) == prefix);
            if (in) atomicAdd(&hist[(key >> shift) & 255u], 1u);
        }
        __syncthreads();
        // parallel inclusive suffix sum: sfx[t] = sum_{u>=t} hist[u]
        sfx[tid] = hist[tid];
        __syncthreads();
        #pragma unroll
        for (int off = 1; off < 256; off <<= 1) {
            unsigned add = (tid + off < 256) ? sfx[tid + off] : 0u;
            __syncthreads();
            sfx[tid] += add;
            __syncthreads();
        }
        unsigned above = (tid < 255) ? sfx[tid + 1] : 0u;
        if (sfx[tid] >= (unsigned)kk && above < (unsigned)kk) {
            sPrefix = (prefix << 8) | (unsigned)tid;
            sKK = kk - (int)above;
        }
        __syncthreads();
        prefix = sPrefix;
        kk = sKK;
        __syncthreads();
    }
    if (tid == 0) {
        sel[b * 2] = prefix;
        sel[b * 2 + 1] = (unsigned)kk;
    }
}

// -------- kW: write 0/1 adj (fp32 + bf16 K-padded), collect exact ties ------
__global__ __launch_bounds__(256) void kW(
    const unsigned* __restrict__ keys, const unsigned* __restrict__ sel,
    unsigned* __restrict__ candCnt, unsigned* __restrict__ cand,
    float* __restrict__ out_base, ushort_t* __restrict__ adjb16)
{
    const int blk = blockIdx.x;
    const int b = blk / NTILES;
    int ti, tj; tile_decode(blk % NTILES, ti, tj);
    const int i0 = ti * 32, j0 = tj * 32;
    const unsigned kth = sel[b * 2];
    const unsigned* kb = keys + (size_t)b * KSTRIDE;
    float* adj = out_base + ADJ_OFF + (size_t)b * NN;
    ushort_t* ab = adjb16 + (size_t)b * (N_SZ * ADJ_STRIDE);

    __shared__ float V[32][33];
    const int r = threadIdx.x >> 5;
    const int c = threadIdx.x & 31;

    #pragma unroll
    for (int s = 0; s < 4; ++s) {
        int rr = r + 8 * s;
        int i = i0 + rr, j = j0 + c;
        if (i < N_SZ && j < N_SZ && i <= j) {
            int base = i * N_SZ - (i * (i - 1)) / 2;
            unsigned key = kb[base + (j - i)];
            float v = (key > kth) ? 1.0f : 0.0f;
            if (key == kth) {
                unsigned p = atomicAdd(&candCnt[b], 1u);
                if (p < CAND_CAP) cand[(size_t)b * CAND_CAP + p] = (unsigned)(i * N_SZ + j);
            }
            V[rr][c] = v;
            if (ti == tj) V[c][rr] = v;
        }
    }
    __syncthreads();
    #pragma unroll
    for (int s = 0; s < 4; ++s) {
        int rr = r + 8 * s;
        int i = i0 + rr, j = j0 + c;
        if (i < N_SZ) {
            float v = (j < N_SZ) ? V[rr][c] : 0.0f;
            if (j < N_SZ) adj[i * N_SZ + j] = v;
            ab[i * ADJ_STRIDE + j] = (v != 0.0f) ? (ushort_t)0x3F80 : (ushort_t)0;
        }
    }
    if (ti != tj) {
        #pragma unroll
        for (int s = 0; s < 4; ++s) {
            int rr = r + 8 * s;
            int i2 = j0 + rr, j2 = i0 + c;
            if (i2 < N_SZ) {
                float v = V[c][rr];
                adj[i2 * N_SZ + j2] = v;
                ab[i2 * ADJ_STRIDE + j2] = (v != 0.0f) ? (ushort_t)0x3F80 : (ushort_t)0;
            }
        }
    }
}

// -------- kT: deterministically include first-kk ties by flat index ---------
__global__ void kT(const unsigned* __restrict__ sel,
                   const unsigned* __restrict__ candCnt,
                   const unsigned* __restrict__ cand,
                   float* __restrict__ out_base, ushort_t* __restrict__ adjb16)
{
    const int b = blockIdx.x;
    if (threadIdx.x != 0) return;
    int kk = (int)sel[b * 2 + 1];
    int cnt = (int)candCnt[b];
    if (cnt > CAND_CAP) cnt = CAND_CAP;
    float* adj = out_base + ADJ_OFF + (size_t)b * NN;
    ushort_t* ab = adjb16 + (size_t)b * (N_SZ * ADJ_STRIDE);
    int take = kk < cnt ? kk : cnt;
    unsigned used[64];
    int nu = 0;
    for (int t = 0; t < take; ++t) {
        unsigned best = 0xFFFFFFFFu;
        for (int q = 0; q < cnt; ++q) {
            unsigned v = cand[(size_t)b * CAND_CAP + q];
            bool skip = false;
            for (int u = 0; u < nu; ++u) if (used[u] == v) { skip = true; break; }
            if (!skip && v < best) best = v;
        }
        if (best == 0xFFFFFFFFu) break;
        if (nu < 64) used[nu++] = best;
        int i = (int)(best / N_SZ), j = (int)(best % N_SZ);
        adj[i * N_SZ + j] = 1.0f;
        adj[j * N_SZ + i] = 1.0f;
        ab[i * ADJ_STRIDE + j] = (ushort_t)0x3F80;
        ab[j * ADJ_STRIDE + i] = (ushort_t)0x3F80;
    }
}

// -------- kWprep: w -> bf16 kgroup layout + zero candCnt --------------------
__global__ __launch_bounds__(256) void kWprep(
    const float* __restrict__ wg, ushort_t* __restrict__ wkg,
    unsigned* __restrict__ candCnt)
{
    if (blockIdx.x == 0) candCnt[threadIdx.x] = 0;   // 256 uints = 1 KB
    int e = blockIdx.x * 256 + threadIdx.x;   // 224 blocks * 256 = 57344
    int kg = e >> 11;
    int rem = e & 2047;
    int n = rem >> 3;
    int ki = rem & 7;
    int k = kg * 8 + ki;
    wkg[e] = (k < FIN) ? f2b(wg[k * OUT_F + n]) : (ushort_t)0;
}

// -------- K2: XW = x @ w_gnn via bf16 MFMA, barrier-free main loop ----------
__global__ __launch_bounds__(256) void k2_mfma(
    const float* __restrict__ x, const ushort_t* __restrict__ wkg,
    ushort_t* __restrict__ xwm)
{
    const int r0 = blockIdx.x * 64;
    const int tid = threadIdx.x;
    const int w = tid >> 6;
    const int l = tid & 63;
    const int g = l >> 4;
    const int r = l & 15;

    __shared__ __align__(16) ushort_t Cs[64 * 256];   // 32 KB epilogue buffer

    f32x4 acc[4][4];
    #pragma unroll
    for (int mf = 0; mf < 4; ++mf)
        #pragma unroll
        for (int nf = 0; nf < 4; ++nf)
            acc[mf][nf] = (f32x4){0.f, 0.f, 0.f, 0.f};

    for (int c = 0; c < 7; ++c) {
        // k>=200 (chunk 6, g>0): clamp addr; B kgroups 25..27 are zero.
        const int koff = (c * 32 + g * 8 < FIN) ? (c * 32 + g * 8) : 0;
        bf16x8 af[4], bf[4];
        #pragma unroll
        for (int mf = 0; mf < 4; ++mf) {
            const float* ap = x + (size_t)(r0 + mf * 16 + r) * FIN + koff;
            float4 lo = *(const float4*)ap;
            float4 hi = *(const float4*)(ap + 4);
            af[mf] = f2b8(lo, hi);
        }
        #pragma unroll
        for (int nf = 0; nf < 4; ++nf)
            bf[nf] = *(const bf16x8*)(wkg + c * 8192 + g * 2048 + (w * 64 + nf * 16 + r) * 8);
        #pragma unroll
        for (int mf = 0; mf < 4; ++mf)
            #pragma unroll
            for (int nf = 0; nf < 4; ++nf)
                acc[mf][nf] = __builtin_amdgcn_mfma_f32_16x16x32_bf16(
                    af[mf], bf[nf], acc[mf][nf], 0, 0, 0);
    }

    // scatter to Cs in kgroup layout (local rows 0..63)
    #pragma unroll
    for (int mf = 0; mf < 4; ++mf) {
        #pragma unroll
        for (int jj = 0; jj < 4; ++jj) {
            int row = mf * 16 + g * 4 + jj;
            #pragma unroll
            for (int nf = 0; nf < 4; ++nf) {
                int col = w * 64 + nf * 16 + r;
                Cs[((row >> 3) << 11) + col * 8 + (row & 7)] = f2b(acc[mf][nf][jj]);
            }
        }
    }
    __syncthreads();
    // linear write-out: 8 local kgroups (8-row groups never cross batch bound)
    #pragma unroll
    for (int kg = 0; kg < 8; ++kg) {
        int grow0 = r0 + kg * 8;
        int bb = grow0 / N_SZ;
        int jb = grow0 % N_SZ;
        ushort_t* dst = xwm + (size_t)bb * XWM_PB + ((jb >> 3) << 11);
        *(int4*)(dst + tid * 8) = *(const int4*)(Cs + (kg << 11) + tid * 8);
    }
}

// -------- K3 fused: emb = relu(adj @ XW) MFMA; out = emb @ w_lin + b --------
// A direct from adjb16 (fragment-ready). XCD-bijective. k4 folded in-register.
__global__ __launch_bounds__(256) void k3_fused(
    const ushort_t* __restrict__ adjb16, const ushort_t* __restrict__ xwm,
    const float* __restrict__ wl, const float* __restrict__ bl,
    float* __restrict__ out_base)
{
    const int blk = blockIdx.x;
    const int b = (blk & 7) + 8 * (blk >> 5);
    const int mt = (blk >> 3) & 3;
    const int tid = threadIdx.x;
    const int w = tid >> 6;
    const int l = tid & 63;
    const int g = l >> 4;
    const int r = l & 15;

    const ushort_t* adjb = adjb16 + (size_t)b * (N_SZ * ADJ_STRIDE);
    const ushort_t* xwb = xwm + (size_t)b * XWM_PB;

    __shared__ float red[4][4][16][8];   // [w][g][slot][cls] = 8 KB

    f32x4 acc[4][4];
    #pragma unroll
    for (int mf = 0; mf < 4; ++mf)
        #pragma unroll
        for (int nf = 0; nf < 4; ++nf)
            acc[mf][nf] = (f32x4){0.f, 0.f, 0.f, 0.f};

    int arows[4];
    #pragma unroll
    for (int mf = 0; mf < 4; ++mf) {
        int row = mt * 64 + mf * 16 + r;
        arows[mf] = (row < N_SZ) ? row : (N_SZ - 1);
    }

    for (int c = 0; c < 7; ++c) {
        bf16x8 af[4], bf[4];
        #pragma unroll
        for (int mf = 0; mf < 4; ++mf)
            af[mf] = *(const bf16x8*)(adjb + arows[mf] * ADJ_STRIDE + c * 32 + g * 8);
        // chunk 6, g>0 reads kgroups 25..27 (next batch / wkg: finite);
        // A is zero there (adjb16 K-padding) so product vanishes.
        #pragma unroll
        for (int nf = 0; nf < 4; ++nf)
            bf[nf] = *(const bf16x8*)(xwb + c * 8192 + g * 2048 + (w * 64 + nf * 16 + r) * 8);
        #pragma unroll
        for (int mf = 0; mf < 4; ++mf)
            #pragma unroll
            for (int nf = 0; nf < 4; ++nf)
                acc[mf][nf] = __builtin_amdgcn_mfma_f32_16x16x32_bf16(
                    af[mf], bf[nf], acc[mf][nf], 0, 0, 0);
    }

    // per-lane w_lin rows for its 4 cols
    float wlv[4][NCLS];
    #pragma unroll
    for (int nf = 0; nf < 4; ++nf) {
        int col = w * 64 + nf * 16 + r;
        #pragma unroll
        for (int cls = 0; cls < NCLS; ++cls) wlv[nf][cls] = wl[col * NCLS + cls];
    }

    // emb store + per-slot class partials + 16-lane-group reduce
    #pragma unroll
    for (int mf = 0; mf < 4; ++mf) {
        #pragma unroll
        for (int j = 0; j < 4; ++j) {
            int rowl = mf * 16 + g * 4 + j;
            int grow = mt * 64 + rowl;
            float e0 = fmaxf(acc[mf][0][j], 0.0f);
            float e1 = fmaxf(acc[mf][1][j], 0.0f);
            float e2 = fmaxf(acc[mf][2][j], 0.0f);
            float e3 = fmaxf(acc[mf][3][j], 0.0f);
            if (grow < N_SZ) {
                size_t rbase = EMB_OFF + ((size_t)b * N_SZ + grow) * OUT_F;
                out_base[rbase + w * 64 + r]      = e0;
                out_base[rbase + w * 64 + 16 + r] = e1;
                out_base[rbase + w * 64 + 32 + r] = e2;
                out_base[rbase + w * 64 + 48 + r] = e3;
            }
            float pr[NCLS];
            #pragma unroll
            for (int cls = 0; cls < NCLS; ++cls)
                pr[cls] = e0 * wlv[0][cls] + e1 * wlv[1][cls]
                        + e2 * wlv[2][cls] + e3 * wlv[3][cls];
            #pragma unroll
            for (int off = 1; off <= 8; off <<= 1) {
                #pragma unroll
                for (int cls = 0; cls < NCLS; ++cls)
                    pr[cls] += __shfl_xor(pr[cls], off, 64);
            }
            if (r < NCLS) red[w][g][mf * 4 + j][r] = pr[r];
        }
    }
    __syncthreads();

    // final combine over waves: 512 outputs, 2 per thread
    #pragma unroll
    for (int e = tid; e < 64 * NCLS; e += 256) {
        int rowl = e >> 3, cls = e & 7;
        int mf = rowl >> 4, rem = rowl & 15, gg = rem >> 2, jj = rem & 3;
        int slot = mf * 4 + jj;
        int grow = mt * 64 + rowl;
        if (grow < N_SZ) {
            float s = red[0][gg][slot][cls] + red[1][gg][slot][cls]
                    + red[2][gg][slot][cls] + red[3][gg][slot][cls] + bl[cls];
            out_base[((size_t)b * N_SZ + grow) * NCLS + cls] = s;
        }
    }
}

extern "C" void kernel_launch(void* const* d_in, const int* in_sizes, int n_in,
                              void* d_out, int out_size, void* d_ws, size_t ws_size,
                              hipStream_t stream) {
    const float* x    = (const float*)d_in[0];
    const float* gu   = (const float*)d_in[1];
    const float* nets = (const float*)d_in[2];
    const float* wg   = (const float*)d_in[3];
    const float* wl   = (const float*)d_in[4];
    const float* bl   = (const float*)d_in[5];
    const int*   nidx = (const int*)d_in[6];
    float* out = (float*)d_out;

    char* ws = (char*)d_ws;
    unsigned* keys    = (unsigned*)(ws + KEYS_OFF_B);
    unsigned* sel     = (unsigned*)(ws + SEL_OFF_B);
    unsigned* candCnt = (unsigned*)(ws + CCNT_OFF_B);
    unsigned* cand    = (unsigned*)(ws + CAND_OFF_B);
    ushort_t* xwm     = (ushort_t*)(ws + KEYS_OFF_B);   // aliases keys; k2 after kT
    ushort_t* wkg     = (ushort_t*)(ws + WKG_OFF_B);
    ushort_t* adjb16  = (ushort_t*)(ws + ADJB16_OFF_B);

    kWprep<<<224, 256, 0, stream>>>(wg, wkg, candCnt);
    kA<<<B_SZ * NTILES, 256, 0, stream>>>(gu, nets, nidx, keys);
    kFinal<<<B_SZ, 256, 0, stream>>>(keys, sel);
    kW<<<B_SZ * NTILES, 256, 0, stream>>>(keys, sel, candCnt, cand, out, adjb16);
    kT<<<B_SZ, 64, 0, stream>>>(sel, candCnt, cand, out, adjb16);

    k2_mfma<<<(B_SZ * N_SZ) / 64, 256, 0, stream>>>(x, wkg, xwm);
    k3_fused<<<B_SZ * 4, 256, 0, stream>>>(adjb16, xwm, wl, bl, out);
}

// Round 11
// 153.270 us; speedup vs baseline: 1.4273x; 1.0459x over previous
//
#include <hip/hip_runtime.h>
#include <math.h>

#define B_SZ 256
#define N_SZ 200
#define NN (N_SZ * N_SZ)          // 40000
#define FIN 200
#define OUT_F 256
#define NCLS 8
#define KSEL 3980
#define NUPPER 20100              // N*(N+1)/2
#define KSTRIDE 20128
#define NT 7                      // ceil(200/32) tiles per dim
#define NTILES 28                 // NT*(NT+1)/2 upper tile pairs
#define CAND_CAP 2048

#define ADJ_STRIDE 224            // adj_bf16 row stride (K-padded zeros beyond 199)
#define KGRP_PB 25                // kgroups per batch (200/8)
#define XWM_PB (KGRP_PB * 2048)   // 51200 elems per batch in mfma layout

#define EMB_OFF (B_SZ * N_SZ * NCLS)               // 409600
#define ADJ_OFF (EMB_OFF + B_SZ * N_SZ * OUT_F)    // 13516800

// ---- ws layout (bytes) ----
// keys:    [0, 20,611,072)        written kA, read kFinal/kW; dead after kW
// sel:     [21,659,648, +2048)    written kFinal; read kW/kT (inside XWM region,
// candCnt: [21,661,696, +1024)     but k2 writes xwm strictly AFTER kT -- safe)
// cand:    [21,662,720, +2,097,152)
// XW_mfma: [0, 26,214,400)        aliases keys; written k2 (after kT), read k3
// w_kgrp:  [26,214,400, +114,688) bf16 w kgroup layout, 28 kgrp (3 zero)
// adjb16:  [26,329,088, +22,937,600) end 49,266,688 (< ws, proven R1-R5)
#define KEYS_OFF_B   0
#define SEL_OFF_B    21659648
#define CCNT_OFF_B   21661696
#define CAND_OFF_B   21662720
#define WKG_OFF_B    26214400
#define ADJB16_OFF_B 26329088

typedef unsigned short ushort_t;
typedef float f32x4 __attribute__((ext_vector_type(4)));
typedef short bf16x8 __attribute__((ext_vector_type(8)));

__device__ __forceinline__ unsigned sortkey(float f) {
    unsigned u = __float_as_uint(f);
    return (u & 0x80000000u) ? ~u : (u | 0x80000000u);
}

__device__ __forceinline__ ushort_t f2b(float f) {   // RNE fp32->bf16
    unsigned u = __float_as_uint(f);
    return (ushort_t)((u + 0x7FFFu + ((u >> 16) & 1u)) >> 16);
}

__device__ __forceinline__ bf16x8 f2b8(float4 lo, float4 hi) {
    bf16x8 r;
    r[0] = (short)f2b(lo.x); r[1] = (short)f2b(lo.y);
    r[2] = (short)f2b(lo.z); r[3] = (short)f2b(lo.w);
    r[4] = (short)f2b(hi.x); r[5] = (short)f2b(hi.y);
    r[6] = (short)f2b(hi.z); r[7] = (short)f2b(hi.w);
    return r;
}

__device__ __forceinline__ void tile_decode(int t, int& ti, int& tj) {
    int a = 0, rem = t;
    while (rem >= NT - a) { rem -= NT - a; ++a; }
    ti = a; tj = a + rem;
}

// -------- kA: compute sym keys (packed upper-tri) ---------------------------
__global__ __launch_bounds__(256) void kA(
    const float* __restrict__ gu, const float* __restrict__ nets,
    const int* __restrict__ net_index, unsigned* __restrict__ keys)
{
    const int blk = blockIdx.x;
    const int b = blk / NTILES;
    int ti, tj; tile_decode(blk % NTILES, ti, tj);
    const int i0 = ti * 32, j0 = tj * 32;
    const float* ub = gu + (size_t)b * NN;
    const float* lb = nets + (size_t)net_index[b] * NN;

    __shared__ float Hij[32][33];
    __shared__ float Hji[32][33];

    const int r = threadIdx.x >> 5;
    const int c = threadIdx.x & 31;

    #pragma unroll
    for (int s = 0; s < 4; ++s) {
        int rr = r + 8 * s;
        int i = i0 + rr, j = j0 + c;
        if (i < N_SZ && j < N_SZ) {
            float u = ub[i * N_SZ + j];
            u = fminf(fmaxf(u, 1e-10f), 1.0f - 1e-10f);
            Hij[rr][c] = lb[i * N_SZ + j] - logf(-logf(u));
        }
        if (ti != tj) {
            int i2 = j0 + rr, j2 = i0 + c;
            if (i2 < N_SZ && j2 < N_SZ) {
                float u = ub[i2 * N_SZ + j2];
                u = fminf(fmaxf(u, 1e-10f), 1.0f - 1e-10f);
                Hji[rr][c] = lb[i2 * N_SZ + j2] - logf(-logf(u));
            }
        }
    }
    __syncthreads();

    unsigned* kb = keys + (size_t)b * KSTRIDE;
    #pragma unroll
    for (int s = 0; s < 4; ++s) {
        int rr = r + 8 * s;
        int i = i0 + rr, j = j0 + c;
        if (i < N_SZ && j < N_SZ && i <= j) {
            float hji = (ti == tj) ? Hij[c][rr] : Hji[c][rr];
            float sv = 0.5f * (Hij[rr][c] + hji);
            int base = i * N_SZ - (i * (i - 1)) / 2;
            kb[base + (j - i)] = sortkey(sv);
        }
    }
}

// -------- kFinal: 4-round radix select, keys LDS-resident, parallel select --
__global__ __launch_bounds__(256) void kFinal(
    const unsigned* __restrict__ keys, unsigned* __restrict__ sel)
{
    const int b = blockIdx.x;
    const int tid = threadIdx.x;
    __shared__ unsigned kl[NUPPER];       // 80.4 KB
    __shared__ unsigned hist[256];
    __shared__ unsigned sfx[256];
    __shared__ unsigned sPrefix;
    __shared__ int sKK;

    const unsigned* kb = keys + (size_t)b * KSTRIDE;
    for (int idx = tid; idx < NUPPER; idx += 256) kl[idx] = kb[idx];

    unsigned prefix = 0;
    int kk = KSEL;
    for (int round = 0; round < 4; ++round) {
        const int shift = 24 - 8 * round;
        hist[tid] = 0;
        __syncthreads();
        for (int idx = tid; idx < NUPPER; idx += 256) {
            unsigned key = kl[idx];
            bool in = (round == 0) || ((key >> (shift + 8)) == prefix);
            if (in) atomicAdd(&hist[(key >> shift) & 255u], 1u);
        }
        __syncthreads();
        // parallel inclusive suffix sum: sfx[t] = sum_{u>=t} hist[u]
        sfx[tid] = hist[tid];
        __syncthreads();
        #pragma unroll
        for (int off = 1; off < 256; off <<= 1) {
            unsigned add = (tid + off < 256) ? sfx[tid + off] : 0u;
            __syncthreads();
            sfx[tid] += add;
            __syncthreads();
        }
        unsigned above = (tid < 255) ? sfx[tid + 1] : 0u;
        if (sfx[tid] >= (unsigned)kk && above < (unsigned)kk) {
            sPrefix = (prefix << 8) | (unsigned)tid;
            sKK = kk - (int)above;
        }
        __syncthreads();
        prefix = sPrefix;
        kk = sKK;
        __syncthreads();
    }
    if (tid == 0) {
        sel[b * 2] = prefix;
        sel[b * 2 + 1] = (unsigned)kk;
    }
}

// -------- kW: write 0/1 adj (fp32 + bf16 K-padded), collect exact ties ------
__global__ __launch_bounds__(256) void kW(
    const unsigned* __restrict__ keys, const unsigned* __restrict__ sel,
    unsigned* __restrict__ candCnt, unsigned* __restrict__ cand,
    float* __restrict__ out_base, ushort_t* __restrict__ adjb16)
{
    const int blk = blockIdx.x;
    const int b = blk / NTILES;
    int ti, tj; tile_decode(blk % NTILES, ti, tj);
    const int i0 = ti * 32, j0 = tj * 32;
    const unsigned kth = sel[b * 2];
    const unsigned* kb = keys + (size_t)b * KSTRIDE;
    float* adj = out_base + ADJ_OFF + (size_t)b * NN;
    ushort_t* ab = adjb16 + (size_t)b * (N_SZ * ADJ_STRIDE);

    __shared__ float V[32][33];
    const int r = threadIdx.x >> 5;
    const int c = threadIdx.x & 31;

    #pragma unroll
    for (int s = 0; s < 4; ++s) {
        int rr = r + 8 * s;
        int i = i0 + rr, j = j0 + c;
        if (i < N_SZ && j < N_SZ && i <= j) {
            int base = i * N_SZ - (i * (i - 1)) / 2;
            unsigned key = kb[base + (j - i)];
            float v = (key > kth) ? 1.0f : 0.0f;
            if (key == kth) {
                unsigned p = atomicAdd(&candCnt[b], 1u);
                if (p < CAND_CAP) cand[(size_t)b * CAND_CAP + p] = (unsigned)(i * N_SZ + j);
            }
            V[rr][c] = v;
            if (ti == tj) V[c][rr] = v;
        }
    }
    __syncthreads();
    #pragma unroll
    for (int s = 0; s < 4; ++s) {
        int rr = r + 8 * s;
        int i = i0 + rr, j = j0 + c;
        if (i < N_SZ) {
            float v = (j < N_SZ) ? V[rr][c] : 0.0f;
            if (j < N_SZ) adj[i * N_SZ + j] = v;
            ab[i * ADJ_STRIDE + j] = (v != 0.0f) ? (ushort_t)0x3F80 : (ushort_t)0;
        }
    }
    if (ti != tj) {
        #pragma unroll
        for (int s = 0; s < 4; ++s) {
            int rr = r + 8 * s;
            int i2 = j0 + rr, j2 = i0 + c;
            if (i2 < N_SZ) {
                float v = V[c][rr];
                adj[i2 * N_SZ + j2] = v;
                ab[i2 * ADJ_STRIDE + j2] = (v != 0.0f) ? (ushort_t)0x3F80 : (ushort_t)0;
            }
        }
    }
}

// -------- kT: deterministically include first-kk ties by flat index ---------
__global__ void kT(const unsigned* __restrict__ sel,
                   const unsigned* __restrict__ candCnt,
                   const unsigned* __restrict__ cand,
                   float* __restrict__ out_base, ushort_t* __restrict__ adjb16)
{
    const int b = blockIdx.x;
    if (threadIdx.x != 0) return;
    int kk = (int)sel[b * 2 + 1];
    int cnt = (int)candCnt[b];
    if (cnt > CAND_CAP) cnt = CAND_CAP;
    float* adj = out_base + ADJ_OFF + (size_t)b * NN;
    ushort_t* ab = adjb16 + (size_t)b * (N_SZ * ADJ_STRIDE);
    int take = kk < cnt ? kk : cnt;
    unsigned used[64];
    int nu = 0;
    for (int t = 0; t < take; ++t) {
        unsigned best = 0xFFFFFFFFu;
        for (int q = 0; q < cnt; ++q) {
            unsigned v = cand[(size_t)b * CAND_CAP + q];
            bool skip = false;
            for (int u = 0; u < nu; ++u) if (used[u] == v) { skip = true; break; }
            if (!skip && v < best) best = v;
        }
        if (best == 0xFFFFFFFFu) break;
        if (nu < 64) used[nu++] = best;
        int i = (int)(best / N_SZ), j = (int)(best % N_SZ);
        adj[i * N_SZ + j] = 1.0f;
        adj[j * N_SZ + i] = 1.0f;
        ab[i * ADJ_STRIDE + j] = (ushort_t)0x3F80;
        ab[j * ADJ_STRIDE + i] = (ushort_t)0x3F80;
    }
}

// -------- kWprep: w -> bf16 kgroup layout + zero candCnt --------------------
__global__ __launch_bounds__(256) void kWprep(
    const float* __restrict__ wg, ushort_t* __restrict__ wkg,
    unsigned* __restrict__ candCnt)
{
    if (blockIdx.x == 0) candCnt[threadIdx.x] = 0;   // 256 uints = 1 KB
    int e = blockIdx.x * 256 + threadIdx.x;   // 224 blocks * 256 = 57344
    int kg = e >> 11;
    int rem = e & 2047;
    int n = rem >> 3;
    int ki = rem & 7;
    int k = kg * 8 + ki;
    wkg[e] = (k < FIN) ? f2b(wg[k * OUT_F + n]) : (ushort_t)0;
}

// -------- K2: XW = x @ w_gnn via bf16 MFMA, barrier-free main loop ----------
__global__ __launch_bounds__(256) void k2_mfma(
    const float* __restrict__ x, const ushort_t* __restrict__ wkg,
    ushort_t* __restrict__ xwm)
{
    const int r0 = blockIdx.x * 64;
    const int tid = threadIdx.x;
    const int w = tid >> 6;
    const int l = tid & 63;
    const int g = l >> 4;
    const int r = l & 15;

    __shared__ __align__(16) ushort_t Cs[64 * 256];   // 32 KB epilogue buffer

    f32x4 acc[4][4];
    #pragma unroll
    for (int mf = 0; mf < 4; ++mf)
        #pragma unroll
        for (int nf = 0; nf < 4; ++nf)
            acc[mf][nf] = (f32x4){0.f, 0.f, 0.f, 0.f};

    for (int c = 0; c < 7; ++c) {
        // k>=200 (chunk 6, g>0): clamp addr; B kgroups 25..27 are zero.
        const int koff = (c * 32 + g * 8 < FIN) ? (c * 32 + g * 8) : 0;
        bf16x8 af[4], bf[4];
        #pragma unroll
        for (int mf = 0; mf < 4; ++mf) {
            const float* ap = x + (size_t)(r0 + mf * 16 + r) * FIN + koff;
            float4 lo = *(const float4*)ap;
            float4 hi = *(const float4*)(ap + 4);
            af[mf] = f2b8(lo, hi);
        }
        #pragma unroll
        for (int nf = 0; nf < 4; ++nf)
            bf[nf] = *(const bf16x8*)(wkg + c * 8192 + g * 2048 + (w * 64 + nf * 16 + r) * 8);
        #pragma unroll
        for (int mf = 0; mf < 4; ++mf)
            #pragma unroll
            for (int nf = 0; nf < 4; ++nf)
                acc[mf][nf] = __builtin_amdgcn_mfma_f32_16x16x32_bf16(
                    af[mf], bf[nf], acc[mf][nf], 0, 0, 0);
    }

    // scatter to Cs in kgroup layout (local rows 0..63)
    #pragma unroll
    for (int mf = 0; mf < 4; ++mf) {
        #pragma unroll
        for (int jj = 0; jj < 4; ++jj) {
            int row = mf * 16 + g * 4 + jj;
            #pragma unroll
            for (int nf = 0; nf < 4; ++nf) {
                int col = w * 64 + nf * 16 + r;
                Cs[((row >> 3) << 11) + col * 8 + (row & 7)] = f2b(acc[mf][nf][jj]);
            }
        }
    }
    __syncthreads();
    // linear write-out: 8 local kgroups (8-row groups never cross batch bound)
    #pragma unroll
    for (int kg = 0; kg < 8; ++kg) {
        int grow0 = r0 + kg * 8;
        int bb = grow0 / N_SZ;
        int jb = grow0 % N_SZ;
        ushort_t* dst = xwm + (size_t)bb * XWM_PB + ((jb >> 3) << 11);
        *(int4*)(dst + tid * 8) = *(const int4*)(Cs + (kg << 11) + tid * 8);
    }
}

// -------- K3 fused v2: 32-row tiles, full A-prefetch, k4 in-register --------
// grid 1792 = 256 batches x 7 mtiles; XCD-bijective: all 7 tiles of a batch
// land on one XCD (xwm[b] L2-hot). A (cold HBM) prefetched in ONE wait.
__global__ __launch_bounds__(256) void k3_fused(
    const ushort_t* __restrict__ adjb16, const ushort_t* __restrict__ xwm,
    const float* __restrict__ wl, const float* __restrict__ bl,
    float* __restrict__ out_base)
{
    const int blk = blockIdx.x;
    const int xcd = blk & 7;
    const int idx = blk >> 3;            // 0..223
    const int b = xcd + 8 * (idx / 7);
    const int mt = idx % 7;              // 7 tiles x 32 rows = 224 (>=200 clamp)
    const int tid = threadIdx.x;
    const int w = tid >> 6;
    const int l = tid & 63;
    const int g = l >> 4;
    const int r = l & 15;

    const ushort_t* adjb = adjb16 + (size_t)b * (N_SZ * ADJ_STRIDE);
    const ushort_t* xwb = xwm + (size_t)b * XWM_PB;

    __shared__ float red[4][4][8][8];    // [w][g][slot][cls] = 4 KB

    // prefetch ALL A fragments (rows cold in HBM): 14 loads, one latency
    int arow0 = mt * 32 + r;       if (arow0 > N_SZ - 1) arow0 = N_SZ - 1;
    int arow1 = mt * 32 + 16 + r;  if (arow1 > N_SZ - 1) arow1 = N_SZ - 1;
    bf16x8 aa[2][7];
    #pragma unroll
    for (int c = 0; c < 7; ++c) {
        aa[0][c] = *(const bf16x8*)(adjb + arow0 * ADJ_STRIDE + c * 32 + g * 8);
        aa[1][c] = *(const bf16x8*)(adjb + arow1 * ADJ_STRIDE + c * 32 + g * 8);
    }

    f32x4 acc[2][4];
    #pragma unroll
    for (int mf = 0; mf < 2; ++mf)
        #pragma unroll
        for (int nf = 0; nf < 4; ++nf)
            acc[mf][nf] = (f32x4){0.f, 0.f, 0.f, 0.f};

    #pragma unroll
    for (int c = 0; c < 7; ++c) {
        bf16x8 bf[4];
        // chunk 6, g>0 reads kgroups 25..27 (next batch / wkg: finite);
        // A is zero there (adjb16 K-padding) so product vanishes.
        #pragma unroll
        for (int nf = 0; nf < 4; ++nf)
            bf[nf] = *(const bf16x8*)(xwb + c * 8192 + g * 2048 + (w * 64 + nf * 16 + r) * 8);
        #pragma unroll
        for (int mf = 0; mf < 2; ++mf)
            #pragma unroll
            for (int nf = 0; nf < 4; ++nf)
                acc[mf][nf] = __builtin_amdgcn_mfma_f32_16x16x32_bf16(
                    aa[mf][c], bf[nf], acc[mf][nf], 0, 0, 0);
    }

    // per-lane w_lin rows for its 4 cols
    float wlv[4][NCLS];
    #pragma unroll
    for (int nf = 0; nf < 4; ++nf) {
        int col = w * 64 + nf * 16 + r;
        #pragma unroll
        for (int cls = 0; cls < NCLS; ++cls) wlv[nf][cls] = wl[col * NCLS + cls];
    }

    // emb store + per-slot class partials + 16-lane-group reduce
    #pragma unroll
    for (int mf = 0; mf < 2; ++mf) {
        #pragma unroll
        for (int j = 0; j < 4; ++j) {
            int rowl = mf * 16 + g * 4 + j;
            int grow = mt * 32 + rowl;
            float e0 = fmaxf(acc[mf][0][j], 0.0f);
            float e1 = fmaxf(acc[mf][1][j], 0.0f);
            float e2 = fmaxf(acc[mf][2][j], 0.0f);
            float e3 = fmaxf(acc[mf][3][j], 0.0f);
            if (grow < N_SZ) {
                size_t rbase = EMB_OFF + ((size_t)b * N_SZ + grow) * OUT_F;
                out_base[rbase + w * 64 + r]      = e0;
                out_base[rbase + w * 64 + 16 + r] = e1;
                out_base[rbase + w * 64 + 32 + r] = e2;
                out_base[rbase + w * 64 + 48 + r] = e3;
            }
            float pr[NCLS];
            #pragma unroll
            for (int cls = 0; cls < NCLS; ++cls)
                pr[cls] = e0 * wlv[0][cls] + e1 * wlv[1][cls]
                        + e2 * wlv[2][cls] + e3 * wlv[3][cls];
            #pragma unroll
            for (int off = 1; off <= 8; off <<= 1) {
                #pragma unroll
                for (int cls = 0; cls < NCLS; ++cls)
                    pr[cls] += __shfl_xor(pr[cls], off, 64);
            }
            if (r < NCLS) red[w][g][mf * 4 + j][r] = pr[r];
        }
    }
    __syncthreads();

    // final combine over waves: 256 outputs, 1 per thread
    {
        int rowl = tid >> 3, cls = tid & 7;
        int mf = rowl >> 4, rem = rowl & 15, gg = rem >> 2, jj = rem & 3;
        int slot = mf * 4 + jj;
        int grow = mt * 32 + rowl;
        if (grow < N_SZ) {
            float s = red[0][gg][slot][cls] + red[1][gg][slot][cls]
                    + red[2][gg][slot][cls] + red[3][gg][slot][cls] + bl[cls];
            out_base[((size_t)b * N_SZ + grow) * NCLS + cls] = s;
        }
    }
}

extern "C" void kernel_launch(void* const* d_in, const int* in_sizes, int n_in,
                              void* d_out, int out_size, void* d_ws, size_t ws_size,
                              hipStream_t stream) {
    const float* x    = (const float*)d_in[0];
    const float* gu   = (const float*)d_in[1];
    const float* nets = (const float*)d_in[2];
    const float* wg   = (const float*)d_in[3];
    const float* wl   = (const float*)d_in[4];
    const float* bl   = (const float*)d_in[5];
    const int*   nidx = (const int*)d_in[6];
    float* out = (float*)d_out;

    char* ws = (char*)d_ws;
    unsigned* keys    = (unsigned*)(ws + KEYS_OFF_B);
    unsigned* sel     = (unsigned*)(ws + SEL_OFF_B);
    unsigned* candCnt = (unsigned*)(ws + CCNT_OFF_B);
    unsigned* cand    = (unsigned*)(ws + CAND_OFF_B);
    ushort_t* xwm     = (ushort_t*)(ws + KEYS_OFF_B);   // aliases keys; k2 after kT
    ushort_t* wkg     = (ushort_t*)(ws + WKG_OFF_B);
    ushort_t* adjb16  = (ushort_t*)(ws + ADJB16_OFF_B);

    kWprep<<<224, 256, 0, stream>>>(wg, wkg, candCnt);
    kA<<<B_SZ * NTILES, 256, 0, stream>>>(gu, nets, nidx, keys);
    kFinal<<<B_SZ, 256, 0, stream>>>(keys, sel);
    kW<<<B_SZ * NTILES, 256, 0, stream>>>(keys, sel, candCnt, cand, out, adjb16);
    kT<<<B_SZ, 64, 0, stream>>>(sel, candCnt, cand, out, adjb16);

    k2_mfma<<<(B_SZ * N_SZ) / 64, 256, 0, stream>>>(x, wkg, xwm);
    k3_fused<<<B_SZ * 7, 256, 0, stream>>>(adjb16, xwm, wl, bl, out);
}

// Round 12
// 148.418 us; speedup vs baseline: 1.4739x; 1.0327x over previous
//
#include <hip/hip_runtime.h>
#include <math.h>

#define B_SZ 256
#define N_SZ 200
#define NN (N_SZ * N_SZ)          // 40000
#define FIN 200
#define OUT_F 256
#define NCLS 8
#define KSEL 3980
#define NUPPER 20100              // N*(N+1)/2
#define KSTRIDE 20128
#define NT 7                      // ceil(200/32) tiles per dim
#define NTILES 28                 // NT*(NT+1)/2 upper tile pairs
#define CAND_CAP 2048

#define ADJ_STRIDE 224            // adj_bf16 row stride (K-padded zeros beyond 199)
#define KGRP_PB 25                // kgroups per batch (200/8)
#define XWM_PB (KGRP_PB * 2048)   // 51200 elems per batch in mfma layout

#define EMB_OFF (B_SZ * N_SZ * NCLS)               // 409600
#define ADJ_OFF (EMB_OFF + B_SZ * N_SZ * OUT_F)    // 13516800

// ---- ws layout (bytes) ----
// keys:    [0, 20,611,072)        written kA, read kFinal/kW; dead after kW
// sel:     [21,659,648, +2048)    written kFinal; read kW/kT (inside XWM region,
// candCnt: [21,661,696, +1024)     but k2 writes xwm strictly AFTER kT -- safe)
// cand:    [21,662,720, +2,097,152)
// XW_mfma: [0, 26,214,400)        aliases keys; written k2 (after kT), read k3
// w_kgrp:  [26,214,400, +114,688) bf16 w kgroup layout, 28 kgrp (3 zero)
// adjb16:  [26,329,088, +22,937,600) end 49,266,688 (< ws, proven R1-R5)
#define KEYS_OFF_B   0
#define SEL_OFF_B    21659648
#define CCNT_OFF_B   21661696
#define CAND_OFF_B   21662720
#define WKG_OFF_B    26214400
#define ADJB16_OFF_B 26329088

typedef unsigned short ushort_t;
typedef float f32x4 __attribute__((ext_vector_type(4)));
typedef short bf16x8 __attribute__((ext_vector_type(8)));
typedef ushort_t u16x4 __attribute__((ext_vector_type(4)));

__device__ __forceinline__ unsigned sortkey(float f) {
    unsigned u = __float_as_uint(f);
    return (u & 0x80000000u) ? ~u : (u | 0x80000000u);
}

__device__ __forceinline__ ushort_t f2b(float f) {   // RNE fp32->bf16
    unsigned u = __float_as_uint(f);
    return (ushort_t)((u + 0x7FFFu + ((u >> 16) & 1u)) >> 16);
}

__device__ __forceinline__ bf16x8 f2b8(float4 lo, float4 hi) {
    bf16x8 r;
    r[0] = (short)f2b(lo.x); r[1] = (short)f2b(lo.y);
    r[2] = (short)f2b(lo.z); r[3] = (short)f2b(lo.w);
    r[4] = (short)f2b(hi.x); r[5] = (short)f2b(hi.y);
    r[6] = (short)f2b(hi.z); r[7] = (short)f2b(hi.w);
    return r;
}

__device__ __forceinline__ void tile_decode(int t, int& ti, int& tj) {
    int a = 0, rem = t;
    while (rem >= NT - a) { rem -= NT - a; ++a; }
    ti = a; tj = a + rem;
}

// -------- kA: sym keys (packed upper-tri) + fused kWprep tail blocks --------
__global__ __launch_bounds__(256) void kA(
    const float* __restrict__ gu, const float* __restrict__ nets,
    const int* __restrict__ net_index, unsigned* __restrict__ keys,
    const float* __restrict__ wg, ushort_t* __restrict__ wkg,
    unsigned* __restrict__ candCnt)
{
    const int blk = blockIdx.x;
    if (blk >= B_SZ * NTILES) {
        // kWprep: w -> bf16 kgroup layout (28 kgroups, 3 zero) + zero candCnt
        int pb = blk - B_SZ * NTILES;    // 0..223
        if (pb == 0) candCnt[threadIdx.x] = 0;
        int e = pb * 256 + threadIdx.x;
        int kg = e >> 11;
        int rem = e & 2047;
        int n = rem >> 3;
        int ki = rem & 7;
        int k = kg * 8 + ki;
        wkg[e] = (k < FIN) ? f2b(wg[k * OUT_F + n]) : (ushort_t)0;
        return;
    }
    const int b = blk / NTILES;
    int ti, tj; tile_decode(blk % NTILES, ti, tj);
    const int i0 = ti * 32, j0 = tj * 32;
    const float* ub = gu + (size_t)b * NN;
    const float* lb = nets + (size_t)net_index[b] * NN;

    __shared__ float Hij[32][33];
    __shared__ float Hji[32][33];

    const int r = threadIdx.x >> 5;
    const int c = threadIdx.x & 31;

    #pragma unroll
    for (int s = 0; s < 4; ++s) {
        int rr = r + 8 * s;
        int i = i0 + rr, j = j0 + c;
        if (i < N_SZ && j < N_SZ) {
            float u = ub[i * N_SZ + j];
            u = fminf(fmaxf(u, 1e-10f), 1.0f - 1e-10f);
            Hij[rr][c] = lb[i * N_SZ + j] - logf(-logf(u));
        }
        if (ti != tj) {
            int i2 = j0 + rr, j2 = i0 + c;
            if (i2 < N_SZ && j2 < N_SZ) {
                float u = ub[i2 * N_SZ + j2];
                u = fminf(fmaxf(u, 1e-10f), 1.0f - 1e-10f);
                Hji[rr][c] = lb[i2 * N_SZ + j2] - logf(-logf(u));
            }
        }
    }
    __syncthreads();

    unsigned* kb = keys + (size_t)b * KSTRIDE;
    #pragma unroll
    for (int s = 0; s < 4; ++s) {
        int rr = r + 8 * s;
        int i = i0 + rr, j = j0 + c;
        if (i < N_SZ && j < N_SZ && i <= j) {
            float hji = (ti == tj) ? Hij[c][rr] : Hji[c][rr];
            float sv = 0.5f * (Hij[rr][c] + hji);
            int base = i * N_SZ - (i * (i - 1)) / 2;
            kb[base + (j - i)] = sortkey(sv);
        }
    }
}

// -------- kFinal: 4-round radix select, keys LDS-resident, parallel select --
__global__ __launch_bounds__(256) void kFinal(
    const unsigned* __restrict__ keys, unsigned* __restrict__ sel)
{
    const int b = blockIdx.x;
    const int tid = threadIdx.x;
    __shared__ unsigned kl[NUPPER];       // 80.4 KB
    __shared__ unsigned hist[256];
    __shared__ unsigned sfx[256];
    __shared__ unsigned sPrefix;
    __shared__ int sKK;

    const unsigned* kb = keys + (size_t)b * KSTRIDE;
    for (int idx = tid; idx < NUPPER; idx += 256) kl[idx] = kb[idx];

    unsigned prefix = 0;
    int kk = KSEL;
    for (int round = 0; round < 4; ++round) {
        const int shift = 24 - 8 * round;
        hist[tid] = 0;
        __syncthreads();
        for (int idx = tid; idx < NUPPER; idx += 256) {
            unsigned key = kl[idx];
            bool in = (round == 0) || ((key >> (shift + 8)) == prefix);
            if (in) atomicAdd(&hist[(key >> shift) & 255u], 1u);
        }
        __syncthreads();
        // parallel inclusive suffix sum: sfx[t] = sum_{u>=t} hist[u]
        sfx[tid] = hist[tid];
        __syncthreads();
        #pragma unroll
        for (int off = 1; off < 256; off <<= 1) {
            unsigned add = (tid + off < 256) ? sfx[tid + off] : 0u;
            __syncthreads();
            sfx[tid] += add;
            __syncthreads();
        }
        unsigned above = (tid < 255) ? sfx[tid + 1] : 0u;
        if (sfx[tid] >= (unsigned)kk && above < (unsigned)kk) {
            sPrefix = (prefix << 8) | (unsigned)tid;
            sKK = kk - (int)above;
        }
        __syncthreads();
        prefix = sPrefix;
        kk = sKK;
        __syncthreads();
    }
    if (tid == 0) {
        sel[b * 2] = prefix;
        sel[b * 2 + 1] = (unsigned)kk;
    }
}

// -------- kW: write 0/1 adj (fp32 + bf16 K-padded), vectorized stores -------
__global__ __launch_bounds__(256) void kW(
    const unsigned* __restrict__ keys, const unsigned* __restrict__ sel,
    unsigned* __restrict__ candCnt, unsigned* __restrict__ cand,
    float* __restrict__ out_base, ushort_t* __restrict__ adjb16)
{
    const int blk = blockIdx.x;
    const int b = blk / NTILES;
    int ti, tj; tile_decode(blk % NTILES, ti, tj);
    const int i0 = ti * 32, j0 = tj * 32;
    const unsigned kth = sel[b * 2];
    const unsigned* kb = keys + (size_t)b * KSTRIDE;
    float* adj = out_base + ADJ_OFF + (size_t)b * NN;
    ushort_t* ab = adjb16 + (size_t)b * (N_SZ * ADJ_STRIDE);

    __shared__ float V[32][33];
    const int r = threadIdx.x >> 5;
    const int c = threadIdx.x & 31;

    #pragma unroll
    for (int s = 0; s < 4; ++s) {
        int rr = r + 8 * s;
        int i = i0 + rr, j = j0 + c;
        if (i < N_SZ && j < N_SZ && i <= j) {
            int base = i * N_SZ - (i * (i - 1)) / 2;
            unsigned key = kb[base + (j - i)];
            float v = (key > kth) ? 1.0f : 0.0f;
            if (key == kth) {
                unsigned p = atomicAdd(&candCnt[b], 1u);
                if (p < CAND_CAP) cand[(size_t)b * CAND_CAP + p] = (unsigned)(i * N_SZ + j);
            }
            V[rr][c] = v;
            if (ti == tj) V[c][rr] = v;
        }
    }
    __syncthreads();

    const int tr = threadIdx.x >> 3;      // 0..31 row in tile
    const int tc = threadIdx.x & 7;       // 0..7 float4 column
    // direct tile (i0, j0): float4 adj + ushort4 adjb16
    {
        int i = i0 + tr;
        if (i < N_SZ) {
            int jb = j0 + tc * 4;
            float v0 = (jb + 0 < N_SZ) ? V[tr][tc * 4 + 0] : 0.0f;
            float v1 = (jb + 1 < N_SZ) ? V[tr][tc * 4 + 1] : 0.0f;
            float v2 = (jb + 2 < N_SZ) ? V[tr][tc * 4 + 2] : 0.0f;
            float v3 = (jb + 3 < N_SZ) ? V[tr][tc * 4 + 3] : 0.0f;
            if (jb + 3 < N_SZ) {
                float4 v4 = {v0, v1, v2, v3};
                *(float4*)(adj + (size_t)i * N_SZ + jb) = v4;
            } else {
                if (jb + 0 < N_SZ) adj[(size_t)i * N_SZ + jb + 0] = v0;
                if (jb + 1 < N_SZ) adj[(size_t)i * N_SZ + jb + 1] = v1;
                if (jb + 2 < N_SZ) adj[(size_t)i * N_SZ + jb + 2] = v2;
            }
            u16x4 a4;
            a4[0] = (v0 != 0.0f) ? (ushort_t)0x3F80 : (ushort_t)0;
            a4[1] = (v1 != 0.0f) ? (ushort_t)0x3F80 : (ushort_t)0;
            a4[2] = (v2 != 0.0f) ? (ushort_t)0x3F80 : (ushort_t)0;
            a4[3] = (v3 != 0.0f) ? (ushort_t)0x3F80 : (ushort_t)0;
            *(u16x4*)(ab + (size_t)i * ADJ_STRIDE + jb) = a4;
        }
    }
    // transposed tile (j0, i0): cols i0..i0+31 always < 200 when ti<tj
    if (ti != tj) {
        int i2 = j0 + tr;
        if (i2 < N_SZ) {
            int jb = i0 + tc * 4;
            float v0 = V[tc * 4 + 0][tr];
            float v1 = V[tc * 4 + 1][tr];
            float v2 = V[tc * 4 + 2][tr];
            float v3 = V[tc * 4 + 3][tr];
            float4 v4 = {v0, v1, v2, v3};
            *(float4*)(adj + (size_t)i2 * N_SZ + jb) = v4;
            u16x4 a4;
            a4[0] = (v0 != 0.0f) ? (ushort_t)0x3F80 : (ushort_t)0;
            a4[1] = (v1 != 0.0f) ? (ushort_t)0x3F80 : (ushort_t)0;
            a4[2] = (v2 != 0.0f) ? (ushort_t)0x3F80 : (ushort_t)0;
            a4[3] = (v3 != 0.0f) ? (ushort_t)0x3F80 : (ushort_t)0;
            *(u16x4*)(ab + (size_t)i2 * ADJ_STRIDE + jb) = a4;
        }
    }
}

// -------- kT: deterministically include first-kk ties by flat index ---------
__global__ void kT(const unsigned* __restrict__ sel,
                   const unsigned* __restrict__ candCnt,
                   const unsigned* __restrict__ cand,
                   float* __restrict__ out_base, ushort_t* __restrict__ adjb16)
{
    const int b = blockIdx.x;
    if (threadIdx.x != 0) return;
    int kk = (int)sel[b * 2 + 1];
    int cnt = (int)candCnt[b];
    if (cnt > CAND_CAP) cnt = CAND_CAP;
    float* adj = out_base + ADJ_OFF + (size_t)b * NN;
    ushort_t* ab = adjb16 + (size_t)b * (N_SZ * ADJ_STRIDE);
    int take = kk < cnt ? kk : cnt;
    unsigned used[64];
    int nu = 0;
    for (int t = 0; t < take; ++t) {
        unsigned best = 0xFFFFFFFFu;
        for (int q = 0; q < cnt; ++q) {
            unsigned v = cand[(size_t)b * CAND_CAP + q];
            bool skip = false;
            for (int u = 0; u < nu; ++u) if (used[u] == v) { skip = true; break; }
            if (!skip && v < best) best = v;
        }
        if (best == 0xFFFFFFFFu) break;
        if (nu < 64) used[nu++] = best;
        int i = (int)(best / N_SZ), j = (int)(best % N_SZ);
        adj[i * N_SZ + j] = 1.0f;
        adj[j * N_SZ + i] = 1.0f;
        ab[i * ADJ_STRIDE + j] = (ushort_t)0x3F80;
        ab[j * ADJ_STRIDE + i] = (ushort_t)0x3F80;
    }
}

// -------- K2: XW = x @ w_gnn via bf16 MFMA, barrier-free main loop ----------
__global__ __launch_bounds__(256) void k2_mfma(
    const float* __restrict__ x, const ushort_t* __restrict__ wkg,
    ushort_t* __restrict__ xwm)
{
    const int r0 = blockIdx.x * 64;
    const int tid = threadIdx.x;
    const int w = tid >> 6;
    const int l = tid & 63;
    const int g = l >> 4;
    const int r = l & 15;

    __shared__ __align__(16) ushort_t Cs[64 * 256];   // 32 KB epilogue buffer

    f32x4 acc[4][4];
    #pragma unroll
    for (int mf = 0; mf < 4; ++mf)
        #pragma unroll
        for (int nf = 0; nf < 4; ++nf)
            acc[mf][nf] = (f32x4){0.f, 0.f, 0.f, 0.f};

    for (int c = 0; c < 7; ++c) {
        // k>=200 (chunk 6, g>0): clamp addr; B kgroups 25..27 are zero.
        const int koff = (c * 32 + g * 8 < FIN) ? (c * 32 + g * 8) : 0;
        bf16x8 af[4], bf[4];
        #pragma unroll
        for (int mf = 0; mf < 4; ++mf) {
            const float* ap = x + (size_t)(r0 + mf * 16 + r) * FIN + koff;
            float4 lo = *(const float4*)ap;
            float4 hi = *(const float4*)(ap + 4);
            af[mf] = f2b8(lo, hi);
        }
        #pragma unroll
        for (int nf = 0; nf < 4; ++nf)
            bf[nf] = *(const bf16x8*)(wkg + c * 8192 + g * 2048 + (w * 64 + nf * 16 + r) * 8);
        #pragma unroll
        for (int mf = 0; mf < 4; ++mf)
            #pragma unroll
            for (int nf = 0; nf < 4; ++nf)
                acc[mf][nf] = __builtin_amdgcn_mfma_f32_16x16x32_bf16(
                    af[mf], bf[nf], acc[mf][nf], 0, 0, 0);
    }

    // scatter to Cs in kgroup layout (local rows 0..63)
    #pragma unroll
    for (int mf = 0; mf < 4; ++mf) {
        #pragma unroll
        for (int jj = 0; jj < 4; ++jj) {
            int row = mf * 16 + g * 4 + jj;
            #pragma unroll
            for (int nf = 0; nf < 4; ++nf) {
                int col = w * 64 + nf * 16 + r;
                Cs[((row >> 3) << 11) + col * 8 + (row & 7)] = f2b(acc[mf][nf][jj]);
            }
        }
    }
    __syncthreads();
    // linear write-out: 8 local kgroups (8-row groups never cross batch bound)
    #pragma unroll
    for (int kg = 0; kg < 8; ++kg) {
        int grow0 = r0 + kg * 8;
        int bb = grow0 / N_SZ;
        int jb = grow0 % N_SZ;
        ushort_t* dst = xwm + (size_t)bb * XWM_PB + ((jb >> 3) << 11);
        *(int4*)(dst + tid * 8) = *(const int4*)(Cs + (kg << 11) + tid * 8);
    }
}

// -------- K3 fused v3: 32-row tiles, A-prefetch, LDS-coalesced emb stores ---
// grid 1792 = 256 batches x 7 mtiles; XCD-bijective: all 7 tiles of a batch
// land on one XCD (xwm[b] L2-hot).
__global__ __launch_bounds__(256) void k3_fused(
    const ushort_t* __restrict__ adjb16, const ushort_t* __restrict__ xwm,
    const float* __restrict__ wl, const float* __restrict__ bl,
    float* __restrict__ out_base)
{
    const int blk = blockIdx.x;
    const int xcd = blk & 7;
    const int idx = blk >> 3;            // 0..223
    const int b = xcd + 8 * (idx / 7);
    const int mt = idx % 7;              // 7 tiles x 32 rows = 224 (>=200 clamp)
    const int tid = threadIdx.x;
    const int w = tid >> 6;
    const int l = tid & 63;
    const int g = l >> 4;
    const int r = l & 15;

    const ushort_t* adjb = adjb16 + (size_t)b * (N_SZ * ADJ_STRIDE);
    const ushort_t* xwb = xwm + (size_t)b * XWM_PB;

    __shared__ __align__(16) float Es[32 * 256];      // 32 KB; red aliases later
    float (*red)[4][8][8] = (float(*)[4][8][8])Es;    // [w][g][slot][cls]

    // prefetch ALL A fragments (rows cold in HBM): 14 loads, one latency
    int arow0 = mt * 32 + r;       if (arow0 > N_SZ - 1) arow0 = N_SZ - 1;
    int arow1 = mt * 32 + 16 + r;  if (arow1 > N_SZ - 1) arow1 = N_SZ - 1;
    bf16x8 aa[2][7];
    #pragma unroll
    for (int c = 0; c < 7; ++c) {
        aa[0][c] = *(const bf16x8*)(adjb + arow0 * ADJ_STRIDE + c * 32 + g * 8);
        aa[1][c] = *(const bf16x8*)(adjb + arow1 * ADJ_STRIDE + c * 32 + g * 8);
    }

    f32x4 acc[2][4];
    #pragma unroll
    for (int mf = 0; mf < 2; ++mf)
        #pragma unroll
        for (int nf = 0; nf < 4; ++nf)
            acc[mf][nf] = (f32x4){0.f, 0.f, 0.f, 0.f};

    #pragma unroll
    for (int c = 0; c < 7; ++c) {
        bf16x8 bf[4];
        // chunk 6, g>0 reads kgroups 25..27 (next batch / wkg: finite);
        // A is zero there (adjb16 K-padding) so product vanishes.
        #pragma unroll
        for (int nf = 0; nf < 4; ++nf)
            bf[nf] = *(const bf16x8*)(xwb + c * 8192 + g * 2048 + (w * 64 + nf * 16 + r) * 8);
        #pragma unroll
        for (int mf = 0; mf < 2; ++mf)
            #pragma unroll
            for (int nf = 0; nf < 4; ++nf)
                acc[mf][nf] = __builtin_amdgcn_mfma_f32_16x16x32_bf16(
                    aa[mf][c], bf[nf], acc[mf][nf], 0, 0, 0);
    }

    // ---- phase A: emb -> Es (relu), then coalesced float4 stores ----
    #pragma unroll
    for (int mf = 0; mf < 2; ++mf) {
        #pragma unroll
        for (int j = 0; j < 4; ++j) {
            int rowl = mf * 16 + g * 4 + j;
            #pragma unroll
            for (int nf = 0; nf < 4; ++nf)
                Es[rowl * 256 + w * 64 + nf * 16 + r] = fmaxf(acc[mf][nf][j], 0.0f);
        }
    }
    __syncthreads();
    #pragma unroll
    for (int q = 0; q < 8; ++q) {
        int e = q * 256 + tid;
        int rowl = e >> 6;               // 64 float4 per row
        int c4 = e & 63;
        int grow = mt * 32 + rowl;
        if (grow < N_SZ) {
            float4 v = *(const float4*)(Es + rowl * 256 + c4 * 4);
            *(float4*)(out_base + EMB_OFF + ((size_t)b * N_SZ + grow) * OUT_F + c4 * 4) = v;
        }
    }
    __syncthreads();   // all Es reads done before red overwrites it

    // ---- phase B: out = emb @ w_lin + b (from acc regs) ----
    float wlv[4][NCLS];
    #pragma unroll
    for (int nf = 0; nf < 4; ++nf) {
        int col = w * 64 + nf * 16 + r;
        #pragma unroll
        for (int cls = 0; cls < NCLS; ++cls) wlv[nf][cls] = wl[col * NCLS + cls];
    }
    #pragma unroll
    for (int mf = 0; mf < 2; ++mf) {
        #pragma unroll
        for (int j = 0; j < 4; ++j) {
            float e0 = fmaxf(acc[mf][0][j], 0.0f);
            float e1 = fmaxf(acc[mf][1][j], 0.0f);
            float e2 = fmaxf(acc[mf][2][j], 0.0f);
            float e3 = fmaxf(acc[mf][3][j], 0.0f);
            float pr[NCLS];
            #pragma unroll
            for (int cls = 0; cls < NCLS; ++cls)
                pr[cls] = e0 * wlv[0][cls] + e1 * wlv[1][cls]
                        + e2 * wlv[2][cls] + e3 * wlv[3][cls];
            #pragma unroll
            for (int off = 1; off <= 8; off <<= 1) {
                #pragma unroll
                for (int cls = 0; cls < NCLS; ++cls)
                    pr[cls] += __shfl_xor(pr[cls], off, 64);
            }
            if (r < NCLS) red[w][g][mf * 4 + j][r] = pr[r];
        }
    }
    __syncthreads();

    // final combine over waves: 256 outputs, 1 per thread
    {
        int rowl = tid >> 3, cls = tid & 7;
        int mf = rowl >> 4, rem = rowl & 15, gg = rem >> 2, jj = rem & 3;
        int slot = mf * 4 + jj;
        int grow = mt * 32 + rowl;
        if (grow < N_SZ) {
            float s = red[0][gg][slot][cls] + red[1][gg][slot][cls]
                    + red[2][gg][slot][cls] + red[3][gg][slot][cls] + bl[cls];
            out_base[((size_t)b * N_SZ + grow) * NCLS + cls] = s;
        }
    }
}

extern "C" void kernel_launch(void* const* d_in, const int* in_sizes, int n_in,
                              void* d_out, int out_size, void* d_ws, size_t ws_size,
                              hipStream_t stream) {
    const float* x    = (const float*)d_in[0];
    const float* gu   = (const float*)d_in[1];
    const float* nets = (const float*)d_in[2];
    const float* wg   = (const float*)d_in[3];
    const float* wl   = (const float*)d_in[4];
    const float* bl   = (const float*)d_in[5];
    const int*   nidx = (const int*)d_in[6];
    float* out = (float*)d_out;

    char* ws = (char*)d_ws;
    unsigned* keys    = (unsigned*)(ws + KEYS_OFF_B);
    unsigned* sel     = (unsigned*)(ws + SEL_OFF_B);
    unsigned* candCnt = (unsigned*)(ws + CCNT_OFF_B);
    unsigned* cand    = (unsigned*)(ws + CAND_OFF_B);
    ushort_t* xwm     = (ushort_t*)(ws + KEYS_OFF_B);   // aliases keys; k2 after kT
    ushort_t* wkg     = (ushort_t*)(ws + WKG_OFF_B);
    ushort_t* adjb16  = (ushort_t*)(ws + ADJB16_OFF_B);

    kA<<<B_SZ * NTILES + 224, 256, 0, stream>>>(gu, nets, nidx, keys, wg, wkg, candCnt);
    kFinal<<<B_SZ, 256, 0, stream>>>(keys, sel);
    kW<<<B_SZ * NTILES, 256, 0, stream>>>(keys, sel, candCnt, cand, out, adjb16);
    kT<<<B_SZ, 64, 0, stream>>>(sel, candCnt, cand, out, adjb16);

    k2_mfma<<<(B_SZ * N_SZ) / 64, 256, 0, stream>>>(x, wkg, xwm);
    k3_fused<<<B_SZ * 7, 256, 0, stream>>>(adjb16, xwm, wl, bl, out);
}